// Round 7
// baseline (1776.778 us; speedup 1.0000x reference)
//
#include <hip/hip_runtime.h>

#define NN 50000
#define NE 800000
#define NIN 32
#define EIN 16
#define HID 128
#define NL 3
#define NG 256
#define TE 64
#define BM 64        // kMlp row tile
#define SCAN_B 196   // ceil(NN/256)
#define EB 128       // edges per aggregation chunk
#define NBLKA (NE/EB + 1)   // 6251
#define ET_MAX 12    // max 16-edge tiles per block (192 edges)
#define SELN 48      // max nodes per block (Poisson(16): P(>48 starts in 128 slots) ~ 0)
#define SELSTR 212   // sel row stride in halfwords (424B -> conflict-free a-frag reads)

typedef unsigned short ushort_t;
typedef __attribute__((ext_vector_type(8))) _Float16 half8;
typedef __attribute__((ext_vector_type(4))) _Float16 f16x4;
typedef __attribute__((ext_vector_type(4))) float f32x4;
typedef __attribute__((ext_vector_type(2))) __fp16 h2;

__device__ __forceinline__ unsigned pkf16(float a, float b){
  h2 h = __builtin_amdgcn_cvt_pkrtz(a, b);
  union{ h2 h; unsigned u; } c; c.h = h; return c.u;
}
__device__ __forceinline__ h2 u2h(unsigned u){
  union{ unsigned u; h2 h; } c; c.u = u; return c.h;
}
__device__ __forceinline__ unsigned h2u(h2 h){
  union{ h2 h; unsigned u; } c; c.h = h; return c.u;
}
__device__ __forceinline__ ushort_t f2h(float x){
  union{ __fp16 h; ushort_t u; } c; c.h = (__fp16)x; return c.u;
}
__device__ __forceinline__ float h2f(ushort_t v){
  union{ ushort_t u; __fp16 h; } c; c.u = v; return (float)c.h;
}
__device__ __forceinline__ f16x4 mk4(unsigned lo, unsigned hi){
  union{ unsigned u[2]; f16x4 v; } c; c.u[0] = lo; c.u[1] = hi; return c.v;
}

typedef const __attribute__((address_space(1))) unsigned gas_t;
typedef __attribute__((address_space(3))) unsigned las_t;
__device__ __forceinline__ void stage16(const void* g, void* l){
  __builtin_amdgcn_global_load_lds((gas_t*)g, (las_t*)l, 16, 0, 0);
}

// ======================= CSR build (dst-sorted) =======================
__global__ void kZero(int* __restrict__ p, int n){
  int i = blockIdx.x*256 + threadIdx.x;
  if (i < n) p[i] = 0;
}

__global__ void kHist(const int* __restrict__ dst, int* __restrict__ cnt){
  int e = blockIdx.x*256 + threadIdx.x;
  if (e < NE) atomicAdd(&cnt[dst[e]], 1);
}

__global__ void kPartSum(const int* __restrict__ cnt, int* __restrict__ psum){
  __shared__ int sm[256];
  int b = blockIdx.x, t = threadIdx.x, i = b*256 + t;
  sm[t] = (i < NN) ? cnt[i] : 0;
  __syncthreads();
  for (int o = 128; o > 0; o >>= 1){
    if (t < o) sm[t] += sm[t + o];
    __syncthreads();
  }
  if (t == 0) psum[b] = sm[0];
}

__global__ __launch_bounds__(256) void kScanPart(const int* __restrict__ psum,
                                                 int* __restrict__ pofs, int* __restrict__ offs){
  __shared__ int sm[256];
  int t = threadIdx.x;
  int v = (t < SCAN_B) ? psum[t] : 0;
  sm[t] = v;
  __syncthreads();
  for (int o = 1; o < 256; o <<= 1){
    int x = (t >= o) ? sm[t - o] : 0;
    __syncthreads();
    sm[t] += x;
    __syncthreads();
  }
  if (t < SCAN_B) pofs[t] = sm[t] - v;
  if (t == 255) offs[NN] = sm[255];
}

__global__ void kScanApply(const int* __restrict__ cnt, const int* __restrict__ pofs,
                           int* __restrict__ offs, int* __restrict__ curs){
  __shared__ int sm[256];
  int b = blockIdx.x, t = threadIdx.x, i = b*256 + t;
  int v = (i < NN) ? cnt[i] : 0;
  sm[t] = v;
  __syncthreads();
  for (int o = 1; o < 256; o <<= 1){
    int x = (t >= o) ? sm[t - o] : 0;
    __syncthreads();
    sm[t] += x;
    __syncthreads();
  }
  int ex = sm[t] - v + pofs[b];
  if (i < NN){ offs[i] = ex; curs[i] = ex; }
}

__global__ void kScatter(const int* __restrict__ dst, const int* __restrict__ src,
                         int* __restrict__ curs, int* __restrict__ perm, int* __restrict__ srcPos){
  int e = blockIdx.x*256 + threadIdx.x;
  if (e < NE){
    int p = atomicAdd(&curs[dst[e]], 1);
    perm[p] = e;
    srcPos[p] = src[e];
  }
}

// eattr rows permuted to CSR order, packed f16 pairs (k-order halfwords)
__global__ void kPermEA(const float* __restrict__ eattr, const int* __restrict__ perm,
                        unsigned* __restrict__ eaPos){
  int gid = blockIdx.x*256 + threadIdx.x;   // NE*2
  if (gid >= NE*2) return;
  int p = gid >> 1, part = gid & 1;
  int e = perm[p];
  const float* row = eattr + (size_t)e*EIN + part*8;
  float4 v0 = *(const float4*)row;
  float4 v1 = *(const float4*)(row + 4);
  uint4 d;
  d.x = pkf16(v0.x, v0.y); d.y = pkf16(v0.z, v0.w);
  d.z = pkf16(v1.x, v1.y); d.w = pkf16(v1.z, v1.w);
  *(uint4*)&eaPos[(size_t)p*8 + part*4] = d;
}

// ======================= W conversions =======================
// wtb: MLP weights f16 transposed+swizzled; wAgg: edge-Lin W^T f16 [l][c][k]
__global__ void kConvW(const float* __restrict__ w1, const float* __restrict__ w2,
                       const float* __restrict__ ew,
                       ushort_t* __restrict__ wtb, ushort_t* __restrict__ wAgg){
  int gid = blockIdx.x*256 + threadIdx.x;
  if (gid < 6*16384){
    int mat = gid >> 14, idx = gid & 16383;
    int k = idx >> 7, n = idx & 127;
    const float* src = (mat < 3) ? (w1 + (size_t)mat*16384) : (w2 + (size_t)(mat-3)*16384);
    wtb[(size_t)mat*16384 + n*128 + (k ^ ((n&7)<<3))] = f2h(src[idx]);
  } else if (gid < 6*16384 + NL*2048){
    int t = gid - 6*16384;
    int l = t >> 11, i = t & 2047;
    int c = i >> 4, k = i & 15;
    wAgg[l*2048 + c*16 + k] = f2h(ew[(size_t)l*2048 + k*128 + c]);
  }
}

// ======================= node embed -> hf (f16) =======================
__global__ void kNodeInit(const float* __restrict__ x, const float* __restrict__ w,
                          const float* __restrict__ b, ushort_t* __restrict__ hf){
  int gid = blockIdx.x*256 + threadIdx.x;   // NN*64
  if (gid >= NN*64) return;
  int n = gid >> 6, c = (gid & 63)*2;
  const float* xr = x + (size_t)n*NIN;
  float a0 = b[c], a1 = b[c+1];
  #pragma unroll
  for (int k = 0; k < NIN; ++k){
    float xv = xr[k];
    a0 = fmaf(xv, w[k*HID + c],     a0);
    a1 = fmaf(xv, w[k*HID + c + 1], a1);
  }
  *(unsigned*)&hf[(size_t)n*HID + c] = pkf16(a0, a1);
}

// ======================= MFMA-based GINE aggregation =======================
// Block b covers nodes starting in edge-chunk [b*EB,(b+1)*EB). MFMA1: E = ea@W; epilogue
// adds gathered h + bias, relu, cvt -> msg fragments (C-layout == MFMA2 b-frag layout for
// K=16, zero cross-lane movement). MFMA2: agg = selector @ msg (f32 accumulate).
__global__ __launch_bounds__(256) void kAggM(
    const ushort_t* __restrict__ hf, const unsigned* __restrict__ eaPos,
    const int* __restrict__ srcPos, const int* __restrict__ offs,
    const ushort_t* __restrict__ wAgg, const float* __restrict__ bl,
    ushort_t* __restrict__ aggb, float* __restrict__ bnS, float* __restrict__ bnQ){
  __shared__ __align__(16) ushort_t eaL[192*24];      // [edge][24hw], 48B stride, 9.2KB
  __shared__ __align__(16) ushort_t WtL[128*24];      // [ch][24hw], 6.1KB
  __shared__ __align__(16) ushort_t selL[SELN*SELSTR];// [node][212hw], 20.4KB
  __shared__ int srcL[ET_MAX*16];
  __shared__ int noffL[SELN+1];
  int tid = threadIdx.x, lane = tid & 63, wv = tid >> 6;
  int b = blockIdx.x;
  if (b == 0 && tid < 128){ bnS[tid] = 0.f; bnQ[tid] = 0.f; }

  // node range: lower_bound(offs, b*EB) .. lower_bound(offs, (b+1)*EB)
  int t0 = b*EB;
  int lo = 0, hi = NN;
  while (lo < hi){ int m = (lo+hi)>>1; if (offs[m] < t0) lo = m+1; else hi = m; }
  int ns = lo;
  lo = ns; hi = NN; int t1 = t0 + EB;
  while (lo < hi){ int m = (lo+hi)>>1; if (offs[m] < t1) lo = m+1; else hi = m; }
  int ne = lo;
  int Nn = ne - ns;
  if (Nn <= 0) return;
  if (Nn > SELN) Nn = SELN;          // probability ~0
  int e0 = offs[ns], e1 = offs[ns + Nn];
  int neb = e1 - e0;                  // <= ~177
  int nets = (neb + 15) >> 4; if (nets > ET_MAX) nets = ET_MAX;

  // ---- stage phase (no internal races; all disjoint) ----
  // ea rows (zero-pad partial tiles)
  for (int i = tid; i < nets*32; i += 256){
    int row = i >> 1, part = i & 1;
    uint4 v = {0,0,0,0};
    if (row < neb) v = *(const uint4*)(eaPos + (size_t)(e0+row)*8 + part*4);
    *(uint4*)((char*)eaL + row*48 + part*16) = v;
  }
  // W^T tile
  if (tid < 256){
    int c = tid >> 1, part = tid & 1;
    *(uint4*)((char*)WtL + c*48 + part*16) = *(const uint4*)(wAgg + c*16 + part*8);
  }
  // src indices (pad with 0 -> safe gather, excluded by selector)
  for (int i = tid; i < nets*16; i += 256)
    srcL[i] = (i < neb) ? srcPos[e0 + i] : 0;
  // node offsets
  if (tid <= Nn) noffL[tid] = offs[ns + tid] - e0;
  // zero selector
  for (int i = tid; i < (SELN*SELSTR)/4; i += 256)
    *(uint2*)((char*)selL + i*8) = make_uint2(0u, 0u);
  __syncthreads();
  // build selector: sel[node][edge] = 1.0h
  if (tid < Nn){
    int eS = noffL[tid], eE = noffL[tid+1];
    for (int e = eS; e < eE; ++e) selL[tid*SELSTR + e] = 0x3C00;
  }
  __syncthreads();

  // ---- compute phase (per wave: 2 channel-tiles = 32 channels) ----
  int l15 = lane & 15, g = lane >> 4;
  int cA = wv*32 + l15, cB = cA + 16;
  f16x4 bfA = *(const f16x4*)((char*)WtL + cA*48 + g*8);
  f16x4 bfB = *(const f16x4*)((char*)WtL + cB*48 + g*8);
  unsigned biasA = pkf16(bl[cA], bl[cA]);
  unsigned biasB = pkf16(bl[cB], bl[cB]);

  f16x4 msgA[ET_MAX], msgB[ET_MAX];
  int4 s4[4]; unsigned hA[4][4], hB[4][4];

  auto LOADH = [&](int et, int slot){
    s4[slot] = *(const int4*)&srcL[et*16 + g*4];
    #pragma unroll
    for (int r = 0; r < 4; ++r){
      int idx[4] = { s4[slot].x, s4[slot].y, s4[slot].z, s4[slot].w };
      hA[slot][r] = hf[(size_t)idx[r]*HID + cA];
      hB[slot][r] = hf[(size_t)idx[r]*HID + cB];
    }
  };

  const f32x4 z4 = {0.f, 0.f, 0.f, 0.f};
  if (nets > 0) LOADH(0, 0);
  if (nets > 1) LOADH(1, 1);
  #pragma unroll
  for (int et = 0; et < ET_MAX; ++et){
    if (et >= nets) break;
    if (et + 2 < nets) LOADH(et + 2, (et + 2) & 3);
    f16x4 af = *(const f16x4*)((char*)eaL + (et*16 + l15)*48 + g*8);
    f32x4 aA = __builtin_amdgcn_mfma_f32_16x16x16f16(af, bfA, z4, 0, 0, 0);
    f32x4 aB = __builtin_amdgcn_mfma_f32_16x16x16f16(af, bfB, z4, 0, 0, 0);
    int sl = et & 3;
    h2 zz; zz[0] = (__fp16)0.f; zz[1] = (__fp16)0.f;
    { unsigned e01 = pkf16(aA[0], aA[1]), e23 = pkf16(aA[2], aA[3]);
      unsigned p01 = (hA[sl][1] << 16) | hA[sl][0];
      unsigned p23 = (hA[sl][3] << 16) | hA[sl][2];
      h2 m01 = __builtin_elementwise_max(u2h(e01) + u2h(biasA) + u2h(p01), zz);
      h2 m23 = __builtin_elementwise_max(u2h(e23) + u2h(biasA) + u2h(p23), zz);
      msgA[et] = mk4(h2u(m01), h2u(m23)); }
    { unsigned e01 = pkf16(aB[0], aB[1]), e23 = pkf16(aB[2], aB[3]);
      unsigned p01 = (hB[sl][1] << 16) | hB[sl][0];
      unsigned p23 = (hB[sl][3] << 16) | hB[sl][2];
      h2 m01 = __builtin_elementwise_max(u2h(e01) + u2h(biasB) + u2h(p01), zz);
      h2 m23 = __builtin_elementwise_max(u2h(e23) + u2h(biasB) + u2h(p23), zz);
      msgB[et] = mk4(h2u(m01), h2u(m23)); }
  }

  // MFMA2: agg[node][c] = sel @ msg
  int ntn = (Nn + 15) >> 4;
  for (int nt = 0; nt < ntn; ++nt){
    f32x4 oA = z4, oB = z4;
    #pragma unroll
    for (int et = 0; et < ET_MAX; ++et){
      if (et >= nets) break;
      f16x4 sf = *(const f16x4*)((char*)selL + (nt*16 + l15)*(SELSTR*2) + (et*16 + g*4)*2);
      oA = __builtin_amdgcn_mfma_f32_16x16x16f16(sf, msgA[et], oA, 0, 0, 0);
      oB = __builtin_amdgcn_mfma_f32_16x16x16f16(sf, msgB[et], oB, 0, 0, 0);
    }
    #pragma unroll
    for (int r = 0; r < 4; ++r){
      int nl = nt*16 + g*4 + r;
      if (nl < Nn){
        size_t base = (size_t)(ns + nl)*HID;
        aggb[base + cA] = f2h(oA[r]);
        aggb[base + cB] = f2h(oB[r]);
      }
    }
  }
}

// ======================= fused MLP via MFMA (f16): A = (1+eps)*h + agg =======================
__global__ __launch_bounds__(256, 1) void kMlp(
    const ushort_t* __restrict__ aggb, const ushort_t* __restrict__ hf,
    const float* __restrict__ epsArr, int layer, float* __restrict__ z2,
    const ushort_t* __restrict__ w1t, const float* __restrict__ b1,
    const ushort_t* __restrict__ w2t, const float* __restrict__ b2,
    float* __restrict__ bnS, float* __restrict__ bnQ){
  __shared__ __align__(16) ushort_t As[BM*128];
  __shared__ __align__(16) ushort_t Bs[128*128];
  __shared__ float red[256];
  int tid  = threadIdx.x;
  int lane = tid & 63;
  int w    = tid >> 6;
  int ln   = tid & 15;
  int q    = (tid >> 4) & 3;
  int rbase = blockIdx.x * BM;
  int m0 = (w >> 1) * 32;
  int wc = (w & 1) * 64;

  const char* gB1 = (const char*)w1t;
  #pragma unroll
  for (int it = 0; it < 8; ++it)
    stage16(gB1 + (w*8192 + it*1024 + lane*16), (char*)Bs + (w*8192 + it*1024));
  {
    _Float16 ep1 = (_Float16)(1.f + epsArr[layer]);
    half8 ep8 = (half8)ep1;
    #pragma unroll
    for (int i = tid; i < BM*16; i += 256){
      int row = i >> 4, c8 = (i & 15) << 3;
      size_t gr = (size_t)(rbase + row)*HID + c8;
      half8 hv = *(const half8*)&hf[gr];
      half8 av = *(const half8*)&aggb[gr];
      half8 o = __builtin_elementwise_fma(hv, ep8, av);
      *(half8*)&As[row*128 + (c8 ^ ((row&7)<<3))] = o;
    }
  }
  __syncthreads();

  f32x4 acc[2][4];
  #pragma unroll
  for (int i = 0; i < 2; ++i)
    #pragma unroll
    for (int j = 0; j < 4; ++j) acc[i][j] = (f32x4)0.f;

  #pragma unroll
  for (int kk = 0; kk < 4; ++kk){
    int kb = kk*32 + q*8;
    half8 af[2], bf[4];
    #pragma unroll
    for (int i = 0; i < 2; ++i){
      int m = m0 + 16*i + ln;
      af[i] = *(const half8*)&As[m*128 + (kb ^ ((m&7)<<3))];
    }
    #pragma unroll
    for (int j = 0; j < 4; ++j){
      int nn = wc + 16*j + ln;
      bf[j] = *(const half8*)&Bs[nn*128 + (kb ^ ((nn&7)<<3))];
    }
    #pragma unroll
    for (int i = 0; i < 2; ++i)
      #pragma unroll
      for (int j = 0; j < 4; ++j)
        acc[i][j] = __builtin_amdgcn_mfma_f32_16x16x32_f16(af[i], bf[j], acc[i][j], 0, 0, 0);
  }
  __syncthreads();

  const char* gB2 = (const char*)w2t;
  #pragma unroll
  for (int it = 0; it < 8; ++it)
    stage16(gB2 + (w*8192 + it*1024 + lane*16), (char*)Bs + (w*8192 + it*1024));
  {
    float b1v[4];
    #pragma unroll
    for (int j = 0; j < 4; ++j) b1v[j] = b1[wc + 16*j + ln];
    #pragma unroll
    for (int i = 0; i < 2; ++i){
      #pragma unroll
      for (int j = 0; j < 4; ++j){
        int kc = wc + 16*j + ln;
        #pragma unroll
        for (int r = 0; r < 4; ++r){
          int m = m0 + 16*i + 4*q + r;
          As[m*128 + (kc ^ ((m&7)<<3))] = f2h(fmaxf(acc[i][j][r] + b1v[j], 0.f));
        }
      }
    }
  }
  #pragma unroll
  for (int i = 0; i < 2; ++i)
    #pragma unroll
    for (int j = 0; j < 4; ++j) acc[i][j] = (f32x4)0.f;
  __syncthreads();

  #pragma unroll
  for (int kk = 0; kk < 4; ++kk){
    int kb = kk*32 + q*8;
    half8 af[2], bf[4];
    #pragma unroll
    for (int i = 0; i < 2; ++i){
      int m = m0 + 16*i + ln;
      af[i] = *(const half8*)&As[m*128 + (kb ^ ((m&7)<<3))];
    }
    #pragma unroll
    for (int j = 0; j < 4; ++j){
      int nn = wc + 16*j + ln;
      bf[j] = *(const half8*)&Bs[nn*128 + (kb ^ ((nn&7)<<3))];
    }
    #pragma unroll
    for (int i = 0; i < 2; ++i)
      #pragma unroll
      for (int j = 0; j < 4; ++j)
        acc[i][j] = __builtin_amdgcn_mfma_f32_16x16x32_f16(af[i], bf[j], acc[i][j], 0, 0, 0);
  }

  float b2v[4];
  #pragma unroll
  for (int j = 0; j < 4; ++j) b2v[j] = b2[wc + 16*j + ln];
  float ps[4], pq[4];
  #pragma unroll
  for (int j = 0; j < 4; ++j){ ps[j] = 0.f; pq[j] = 0.f; }
  #pragma unroll
  for (int i = 0; i < 2; ++i){
    #pragma unroll
    for (int r = 0; r < 4; ++r){
      int rg = rbase + m0 + 16*i + 4*q + r;
      if (rg < NN){
        #pragma unroll
        for (int j = 0; j < 4; ++j){
          float v = acc[i][j][r] + b2v[j];
          z2[(size_t)rg*HID + wc + 16*j + ln] = v;
          ps[j] += v; pq[j] += v*v;
        }
      }
    }
  }
  red[tid] = 0.f;
  if (tid < 128) red[128 + tid] = 0.f;
  __syncthreads();
  #pragma unroll
  for (int j = 0; j < 4; ++j){
    int c = wc + 16*j + ln;
    atomicAdd(&red[c], ps[j]);
    atomicAdd(&red[128 + c], pq[j]);
  }
  __syncthreads();
  if (tid < 128){
    atomicAdd(&bnS[tid], red[tid]);
    atomicAdd(&bnQ[tid], red[128 + tid]);
  }
}

// ======================= BN apply + ReLU -> hf (f16) =======================
__global__ void kBn(const float* __restrict__ z2, const float* __restrict__ bnS,
                    const float* __restrict__ bnQ, const float* __restrict__ gamma,
                    const float* __restrict__ beta, ushort_t* __restrict__ hf){
  int gid = blockIdx.x*256 + threadIdx.x;   // NN*64
  if (gid >= NN*64) return;
  int r = gid >> 6, c = (gid & 63)*2;
  float2 zv = *(const float2*)&z2[(size_t)r*HID + c];
  float2 sS = *(const float2*)&bnS[c];
  float2 sQ = *(const float2*)&bnQ[c];
  float2 gm = *(const float2*)&gamma[c];
  float2 bt = *(const float2*)&beta[c];
  float m0 = sS.x*(1.f/NN), m1 = sS.y*(1.f/NN);
  float v0 = sQ.x*(1.f/NN) - m0*m0, v1 = sQ.y*(1.f/NN) - m1*m1;
  float o0 = fmaxf((zv.x - m0)*rsqrtf(v0 + 1e-5f)*gm.x + bt.x, 0.f);
  float o1 = fmaxf((zv.y - m1)*rsqrtf(v1 + 1e-5f)*gm.y + bt.y, 0.f);
  *(unsigned*)&hf[(size_t)r*HID + c] = pkf16(o0, o1);
}

// ======================= pool =======================
__global__ __launch_bounds__(192) void kPool(const ushort_t* __restrict__ hf, const int* __restrict__ bid,
                      const int* __restrict__ tidx, const float* __restrict__ temb,
                      float* __restrict__ g){
  int b = blockIdx.x, t = threadIdx.x;
  int lo = 0, hi = NN;
  while (lo < hi){ int m = (lo + hi) >> 1; if (bid[m] < b) lo = m + 1; else hi = m; }
  int s = lo;
  lo = 0; hi = NN;
  while (lo < hi){ int m = (lo + hi) >> 1; if (bid[m] < b + 1) lo = m + 1; else hi = m; }
  int e = lo;
  if (t < HID){
    float acc = 0.f;
    for (int n = s; n < e; ++n) acc += h2f(hf[(size_t)n*HID + t]);
    g[b*192 + t] = acc;
  } else {
    int j = t - HID;
    g[b*192 + HID + j] = temb[tidx[b]*TE + j];
  }
}

// ======================= head MLP =======================
__global__ __launch_bounds__(128) void kHead(const float* __restrict__ g,
    const float* __restrict__ w1, const float* __restrict__ b1,
    const float* __restrict__ w2, const float* __restrict__ b2,
    const float* __restrict__ w3, const float* __restrict__ b3,
    float* __restrict__ out){
  __shared__ float gv[192];
  __shared__ float t1[128];
  __shared__ float t2[64];
  int b = blockIdx.x, t = threadIdx.x;
  gv[t] = g[b*192 + t];
  if (t < 64) gv[128 + t] = g[b*192 + 128 + t];
  __syncthreads();
  float acc = b1[t];
  for (int k = 0; k < 192; ++k) acc = fmaf(gv[k], w1[k*HID + t], acc);
  t1[t] = fmaxf(acc, 0.f);
  __syncthreads();
  if (t < 64){
    float a2 = b2[t];
    for (int k = 0; k < 128; ++k) a2 = fmaf(t1[k], w2[k*64 + t], a2);
    t2[t] = fmaxf(a2, 0.f);
  }
  __syncthreads();
  if (t == 0){
    float s = b3[0];
    for (int k = 0; k < 64; ++k) s = fmaf(t2[k], w3[k], s);
    out[b] = s;
  }
}

// ======================= launch =======================
extern "C" void kernel_launch(void* const* d_in, const int* in_sizes, int n_in,
                              void* d_out, int out_size, void* d_ws, size_t ws_size,
                              hipStream_t stream){
  const float* x     = (const float*)d_in[0];
  const int*   ei    = (const int*)  d_in[1];
  const float* eattr = (const float*)d_in[2];
  const int*   bids  = (const int*)  d_in[3];
  const int*   tgt   = (const int*)  d_in[4];
  const float* nw    = (const float*)d_in[5];
  const float* nb    = (const float*)d_in[6];
  const float* eps   = (const float*)d_in[7];
  const float* ew    = (const float*)d_in[8];
  const float* eb    = (const float*)d_in[9];
  const float* w1    = (const float*)d_in[10];
  const float* bb1   = (const float*)d_in[11];
  const float* w2    = (const float*)d_in[12];
  const float* bb2   = (const float*)d_in[13];
  const float* gam   = (const float*)d_in[14];
  const float* bet   = (const float*)d_in[15];
  const float* temb  = (const float*)d_in[16];
  const float* h1w   = (const float*)d_in[17];
  const float* h1b   = (const float*)d_in[18];
  const float* h2w   = (const float*)d_in[19];
  const float* h2b   = (const float*)d_in[20];
  const float* h3w   = (const float*)d_in[21];
  const float* h3b   = (const float*)d_in[22];
  float* out = (float*)d_out;

  ushort_t* aggb = (ushort_t*)d_ws;                     // (NN+64)*128
  ushort_t* wtb  = aggb + (size_t)(NN + 64)*HID;        // 6*16384
  ushort_t* wAgg = wtb + (size_t)6*16384;               // NL*2048
  ushort_t* hf   = wAgg + (size_t)NL*2048;              // (NN+64)*128
  unsigned* eaPos = (unsigned*)(hf + (size_t)(NN + 64)*HID); // NE*8
  float* z2  = (float*)(eaPos + (size_t)NE*8);          // NN*128
  float* g   = z2 + (size_t)NN*HID;                     // NG*192
  float* bnS = g  + (size_t)NG*192;                     // 128
  float* bnQ = bnS + HID;                               // 128
  int* offs  = (int*)(bnQ + HID);                       // NN+1
  int* cnt   = offs + NN + 1;                           // NN
  int* curs  = cnt + NN;                                // NN
  int* perm  = curs + NN;                               // NE
  int* srcPos= perm + NE;                               // NE
  int* psum  = srcPos + NE;                             // 256
  int* pofs  = psum + 256;                              // 256

  const int* esrc = ei;
  const int* edst = ei + NE;

  kConvW   <<<(6*16384 + NL*2048 + 255)/256, 256, 0, stream>>>(w1, w2, ew, wtb, wAgg);
  kZero    <<<(NN + 255)/256, 256, 0, stream>>>(cnt, NN);
  kHist    <<<(NE + 255)/256, 256, 0, stream>>>(edst, cnt);
  kPartSum <<<SCAN_B, 256, 0, stream>>>(cnt, psum);
  kScanPart<<<1, 256, 0, stream>>>(psum, pofs, offs);
  kScanApply<<<SCAN_B, 256, 0, stream>>>(cnt, pofs, offs, curs);
  kScatter <<<(NE + 255)/256, 256, 0, stream>>>(edst, esrc, curs, perm, srcPos);
  kPermEA  <<<(NE*2 + 255)/256, 256, 0, stream>>>(eattr, perm, eaPos);
  kNodeInit<<<(NN*64 + 255)/256, 256, 0, stream>>>(x, nw, nb, hf);

  for (int l = 0; l < NL; ++l){
    kAggM<<<NBLKA, 256, 0, stream>>>(hf, eaPos, srcPos, offs,
                                 wAgg + (size_t)l*2048, eb + (size_t)l*HID,
                                 aggb, bnS, bnQ);
    kMlp<<<(NN + BM - 1)/BM, 256, 0, stream>>>(aggb, hf, eps, l, z2,
                                 wtb + (size_t)l*16384, bb1 + (size_t)l*HID,
                                 wtb + (size_t)(3+l)*16384, bb2 + (size_t)l*HID,
                                 bnS, bnQ);
    kBn<<<(NN*64 + 255)/256, 256, 0, stream>>>(z2, bnS, bnQ,
                                 gam + (size_t)l*HID, bet + (size_t)l*HID, hf);
  }

  kPool<<<NG, 192, 0, stream>>>(hf, bids, tgt, temb, g);
  kHead<<<NG, 128, 0, stream>>>(g, h1w, h1b, h2w, h2b, h3w, h3b, out);
}

// Round 8
// 609.464 us; speedup vs baseline: 2.9153x; 2.9153x over previous
//
#include <hip/hip_runtime.h>

#define NN 50000
#define NE 800000
#define NIN 32
#define EIN 16
#define HID 128
#define NL 3
#define NG 256
#define TE 64
#define BM 64        // kMlp row tile
#define SCAN_B 196   // ceil(NN/256)
#define NB_AGG 4096  // kAgg blocks (x4 waves)

typedef unsigned short ushort_t;
typedef __attribute__((ext_vector_type(8))) _Float16 half8;
typedef __attribute__((ext_vector_type(4))) float f32x4;
typedef __attribute__((ext_vector_type(2))) __fp16 h2;

__device__ __forceinline__ unsigned pkf16(float a, float b){
  h2 h = __builtin_amdgcn_cvt_pkrtz(a, b);
  union{ h2 h; unsigned u; } c; c.h = h; return c.u;
}
__device__ __forceinline__ h2 u2h(unsigned u){
  union{ unsigned u; h2 h; } c; c.u = u; return c.h;
}
__device__ __forceinline__ ushort_t f2h(float x){
  union{ __fp16 h; ushort_t u; } c; c.h = (__fp16)x; return c.u;
}
__device__ __forceinline__ float h2f(ushort_t v){
  union{ ushort_t u; __fp16 h; } c; c.u = v; return (float)c.h;
}

typedef const __attribute__((address_space(1))) unsigned gas_t;
typedef __attribute__((address_space(3))) unsigned las_t;
__device__ __forceinline__ void stage16(const void* g, void* l){
  __builtin_amdgcn_global_load_lds((gas_t*)g, (las_t*)l, 16, 0, 0);
}

// ======================= CSR build (dst-sorted) =======================
__global__ void kZero(int* __restrict__ p, int n){
  int i = blockIdx.x*256 + threadIdx.x;
  if (i < n) p[i] = 0;
}

__global__ void kHist(const int* __restrict__ dst, int* __restrict__ cnt){
  int e = blockIdx.x*256 + threadIdx.x;
  if (e < NE) atomicAdd(&cnt[dst[e]], 1);
}

__global__ void kPartSum(const int* __restrict__ cnt, int* __restrict__ psum){
  __shared__ int sm[256];
  int b = blockIdx.x, t = threadIdx.x, i = b*256 + t;
  sm[t] = (i < NN) ? cnt[i] : 0;
  __syncthreads();
  for (int o = 128; o > 0; o >>= 1){
    if (t < o) sm[t] += sm[t + o];
    __syncthreads();
  }
  if (t == 0) psum[b] = sm[0];
}

__global__ __launch_bounds__(256) void kScanPart(const int* __restrict__ psum,
                                                 int* __restrict__ pofs, int* __restrict__ offs){
  __shared__ int sm[256];
  int t = threadIdx.x;
  int v = (t < SCAN_B) ? psum[t] : 0;
  sm[t] = v;
  __syncthreads();
  for (int o = 1; o < 256; o <<= 1){
    int x = (t >= o) ? sm[t - o] : 0;
    __syncthreads();
    sm[t] += x;
    __syncthreads();
  }
  if (t < SCAN_B) pofs[t] = sm[t] - v;
  if (t == 255) offs[NN] = sm[255];
}

__global__ void kScanApply(const int* __restrict__ cnt, const int* __restrict__ pofs,
                           int* __restrict__ offs, int* __restrict__ curs){
  __shared__ int sm[256];
  int b = blockIdx.x, t = threadIdx.x, i = b*256 + t;
  int v = (i < NN) ? cnt[i] : 0;
  sm[t] = v;
  __syncthreads();
  for (int o = 1; o < 256; o <<= 1){
    int x = (t >= o) ? sm[t - o] : 0;
    __syncthreads();
    sm[t] += x;
    __syncthreads();
  }
  int ex = sm[t] - v + pofs[b];
  if (i < NN){ offs[i] = ex; curs[i] = ex; }
}

__global__ void kScatter(const int* __restrict__ dst, const int* __restrict__ src,
                         int* __restrict__ curs, int* __restrict__ perm, int* __restrict__ srcPos){
  int e = blockIdx.x*256 + threadIdx.x;
  if (e < NE){
    int p = atomicAdd(&curs[dst[e]], 1);
    perm[p] = e;
    srcPos[p] = src[e];
  }
}

// eattr rows permuted to CSR order, packed f16 k-pairs
__global__ void kPermEA(const float* __restrict__ eattr, const int* __restrict__ perm,
                        unsigned* __restrict__ eaPos){
  int gid = blockIdx.x*256 + threadIdx.x;   // NE*2
  if (gid >= NE*2) return;
  int p = gid >> 1, part = gid & 1;
  int e = perm[p];
  const float* row = eattr + (size_t)e*EIN + part*8;
  float4 v0 = *(const float4*)row;
  float4 v1 = *(const float4*)(row + 4);
  uint4 d;
  d.x = pkf16(v0.x, v0.y); d.y = pkf16(v0.z, v0.w);
  d.z = pkf16(v1.x, v1.y); d.w = pkf16(v1.z, v1.w);
  *(uint4*)&eaPos[(size_t)p*8 + part*4] = d;
}

// ======================= W -> f16, transposed + pre-swizzled =======================
__global__ void kConvW(const float* __restrict__ w1, const float* __restrict__ w2,
                       ushort_t* __restrict__ wtb){
  int gid = blockIdx.x*256 + threadIdx.x;
  if (gid >= 6*16384) return;
  int mat = gid >> 14, idx = gid & 16383;
  int k = idx >> 7, n = idx & 127;
  const float* src = (mat < 3) ? (w1 + (size_t)mat*16384) : (w2 + (size_t)(mat-3)*16384);
  wtb[(size_t)mat*16384 + n*128 + (k ^ ((n&7)<<3))] = f2h(src[idx]);
}

// ======================= node embed -> hf (f16) =======================
__global__ void kNodeInit(const float* __restrict__ x, const float* __restrict__ w,
                          const float* __restrict__ b, ushort_t* __restrict__ hf){
  int gid = blockIdx.x*256 + threadIdx.x;   // NN*64
  if (gid >= NN*64) return;
  int n = gid >> 6, c = (gid & 63)*2;
  const float* xr = x + (size_t)n*NIN;
  float a0 = b[c], a1 = b[c+1];
  #pragma unroll
  for (int k = 0; k < NIN; ++k){
    float xv = xr[k];
    a0 = fmaf(xv, w[k*HID + c],     a0);
    a1 = fmaf(xv, w[k*HID + c + 1], a1);
  }
  *(unsigned*)&hf[(size_t)n*HID + c] = pkf16(a0, a1);
}

// ======================= GINE aggregate: wave-per-node (R4 structure, f16) =======================
// LDS-staged ea (k-pair packed) + srcs; 16-deep register prefetch of h gathers.
// Writes only agg = sum_e relu(h_src + ea@W + b); self-term folded into kMlp.
__global__ __launch_bounds__(256) void kAgg(
    const ushort_t* __restrict__ hf, const unsigned* __restrict__ eaPos,
    const int* __restrict__ srcPos, const int* __restrict__ offs,
    const float* __restrict__ Wl, const float* __restrict__ bl,
    ushort_t* __restrict__ aggb, float* __restrict__ bnS, float* __restrict__ bnQ){
  __shared__ unsigned easu[4][16][8];   // [wave][edge][8 u32 = 16 f16 k-values]
  __shared__ int srcsS[4][16];
  int tid = threadIdx.x, lane = tid & 63, wv = tid >> 6;
  if (blockIdx.x == 0 && tid < 128){ bnS[tid] = 0.f; bnQ[tid] = 0.f; }
  int c0 = 2*lane;
  // k-pair packed W columns: wA for channel c0, wB for c0+1
  h2 wA[8], wB[8];
  #pragma unroll
  for (int kk = 0; kk < 8; ++kk){
    wA[kk] = __builtin_amdgcn_cvt_pkrtz(Wl[(2*kk)*HID + c0],     Wl[(2*kk+1)*HID + c0]);
    wB[kk] = __builtin_amdgcn_cvt_pkrtz(Wl[(2*kk)*HID + c0 + 1], Wl[(2*kk+1)*HID + c0 + 1]);
  }
  float b0 = bl[c0], b1 = bl[c0+1];

  for (int n = blockIdx.x*4 + wv; n < NN; n += NB_AGG*4){
    int s0 = offs[n], s1 = offs[n+1];
    float acc0 = 0.f, acc1 = 0.f;

    auto BODY = [&](int i, unsigned hs){
      const uint4* A = (const uint4*)&easu[wv][i][0];
      uint4 e0 = A[0], e1 = A[1];
      h2 za; za[0] = (__fp16)0.f; za[1] = (__fp16)0.f;
      h2 accA = za, accB = za;
      accA = __builtin_elementwise_fma(u2h(e0.x), wA[0], accA);
      accB = __builtin_elementwise_fma(u2h(e0.x), wB[0], accB);
      accA = __builtin_elementwise_fma(u2h(e0.y), wA[1], accA);
      accB = __builtin_elementwise_fma(u2h(e0.y), wB[1], accB);
      accA = __builtin_elementwise_fma(u2h(e0.z), wA[2], accA);
      accB = __builtin_elementwise_fma(u2h(e0.z), wB[2], accB);
      accA = __builtin_elementwise_fma(u2h(e0.w), wA[3], accA);
      accB = __builtin_elementwise_fma(u2h(e0.w), wB[3], accB);
      accA = __builtin_elementwise_fma(u2h(e1.x), wA[4], accA);
      accB = __builtin_elementwise_fma(u2h(e1.x), wB[4], accB);
      accA = __builtin_elementwise_fma(u2h(e1.y), wA[5], accA);
      accB = __builtin_elementwise_fma(u2h(e1.y), wB[5], accB);
      accA = __builtin_elementwise_fma(u2h(e1.z), wA[6], accA);
      accB = __builtin_elementwise_fma(u2h(e1.z), wB[6], accB);
      accA = __builtin_elementwise_fma(u2h(e1.w), wA[7], accA);
      accB = __builtin_elementwise_fma(u2h(e1.w), wB[7], accB);
      float ev0 = (float)accA[0] + (float)accA[1] + b0;
      float ev1 = (float)accB[0] + (float)accB[1] + b1;
      float h0v = h2f((ushort_t)(hs & 0xffffu));
      float h1v = h2f((ushort_t)(hs >> 16));
      acc0 += fmaxf(h0v + ev0, 0.f);
      acc1 += fmaxf(h1v + ev1, 0.f);
    };

    for (int j = s0; j < s1; j += 16){
      int cnt = min(16, s1 - j);
      if (lane < cnt) srcsS[wv][lane] = srcPos[j + lane];
      if (lane < 4*cnt){
        int r = lane >> 2, part = lane & 3;
        *(uint2*)&easu[wv][r][part*2] = *(const uint2*)&eaPos[(size_t)(j + r)*8 + part*2];
      }
      asm volatile("s_waitcnt lgkmcnt(0)" ::: "memory");
      if (cnt == 16){
        unsigned hsv[16];
        #pragma unroll
        for (int i = 0; i < 16; ++i)
          hsv[i] = *(const unsigned*)&hf[(size_t)srcsS[wv][i]*HID + c0];
        #pragma unroll
        for (int i = 0; i < 16; ++i) BODY(i, hsv[i]);
      } else {
        for (int i = 0; i < cnt; ++i){
          unsigned hs = *(const unsigned*)&hf[(size_t)srcsS[wv][i]*HID + c0];
          BODY(i, hs);
        }
      }
      asm volatile("s_waitcnt lgkmcnt(0)" ::: "memory");  // easu reads done before overwrite
    }
    *(unsigned*)&aggb[(size_t)n*HID + c0] = pkf16(acc0, acc1);
  }
}

// ======================= fused MLP via MFMA (f16): A = (1+eps)*h + agg =======================
__global__ __launch_bounds__(256, 1) void kMlp(
    const ushort_t* __restrict__ aggb, const ushort_t* __restrict__ hf,
    const float* __restrict__ epsArr, int layer, float* __restrict__ z2,
    const ushort_t* __restrict__ w1t, const float* __restrict__ b1,
    const ushort_t* __restrict__ w2t, const float* __restrict__ b2,
    float* __restrict__ bnS, float* __restrict__ bnQ){
  __shared__ __align__(16) ushort_t As[BM*128];
  __shared__ __align__(16) ushort_t Bs[128*128];
  __shared__ float red[256];
  int tid  = threadIdx.x;
  int lane = tid & 63;
  int w    = tid >> 6;
  int ln   = tid & 15;
  int q    = (tid >> 4) & 3;
  int rbase = blockIdx.x * BM;
  int m0 = (w >> 1) * 32;
  int wc = (w & 1) * 64;

  const char* gB1 = (const char*)w1t;
  #pragma unroll
  for (int it = 0; it < 8; ++it)
    stage16(gB1 + (w*8192 + it*1024 + lane*16), (char*)Bs + (w*8192 + it*1024));
  {
    _Float16 ep1 = (_Float16)(1.f + epsArr[layer]);
    half8 ep8 = (half8)ep1;
    #pragma unroll
    for (int i = tid; i < BM*16; i += 256){
      int row = i >> 4, c8 = (i & 15) << 3;
      size_t gr = (size_t)(rbase + row)*HID + c8;
      half8 hv = *(const half8*)&hf[gr];
      half8 av = *(const half8*)&aggb[gr];
      half8 o = __builtin_elementwise_fma(hv, ep8, av);
      *(half8*)&As[row*128 + (c8 ^ ((row&7)<<3))] = o;
    }
  }
  __syncthreads();

  f32x4 acc[2][4];
  #pragma unroll
  for (int i = 0; i < 2; ++i)
    #pragma unroll
    for (int j = 0; j < 4; ++j) acc[i][j] = (f32x4)0.f;

  #pragma unroll
  for (int kk = 0; kk < 4; ++kk){
    int kb = kk*32 + q*8;
    half8 af[2], bf[4];
    #pragma unroll
    for (int i = 0; i < 2; ++i){
      int m = m0 + 16*i + ln;
      af[i] = *(const half8*)&As[m*128 + (kb ^ ((m&7)<<3))];
    }
    #pragma unroll
    for (int j = 0; j < 4; ++j){
      int nn = wc + 16*j + ln;
      bf[j] = *(const half8*)&Bs[nn*128 + (kb ^ ((nn&7)<<3))];
    }
    #pragma unroll
    for (int i = 0; i < 2; ++i)
      #pragma unroll
      for (int j = 0; j < 4; ++j)
        acc[i][j] = __builtin_amdgcn_mfma_f32_16x16x32_f16(af[i], bf[j], acc[i][j], 0, 0, 0);
  }
  __syncthreads();

  const char* gB2 = (const char*)w2t;
  #pragma unroll
  for (int it = 0; it < 8; ++it)
    stage16(gB2 + (w*8192 + it*1024 + lane*16), (char*)Bs + (w*8192 + it*1024));
  {
    float b1v[4];
    #pragma unroll
    for (int j = 0; j < 4; ++j) b1v[j] = b1[wc + 16*j + ln];
    #pragma unroll
    for (int i = 0; i < 2; ++i){
      #pragma unroll
      for (int j = 0; j < 4; ++j){
        int kc = wc + 16*j + ln;
        #pragma unroll
        for (int r = 0; r < 4; ++r){
          int m = m0 + 16*i + 4*q + r;
          As[m*128 + (kc ^ ((m&7)<<3))] = f2h(fmaxf(acc[i][j][r] + b1v[j], 0.f));
        }
      }
    }
  }
  #pragma unroll
  for (int i = 0; i < 2; ++i)
    #pragma unroll
    for (int j = 0; j < 4; ++j) acc[i][j] = (f32x4)0.f;
  __syncthreads();

  #pragma unroll
  for (int kk = 0; kk < 4; ++kk){
    int kb = kk*32 + q*8;
    half8 af[2], bf[4];
    #pragma unroll
    for (int i = 0; i < 2; ++i){
      int m = m0 + 16*i + ln;
      af[i] = *(const half8*)&As[m*128 + (kb ^ ((m&7)<<3))];
    }
    #pragma unroll
    for (int j = 0; j < 4; ++j){
      int nn = wc + 16*j + ln;
      bf[j] = *(const half8*)&Bs[nn*128 + (kb ^ ((nn&7)<<3))];
    }
    #pragma unroll
    for (int i = 0; i < 2; ++i)
      #pragma unroll
      for (int j = 0; j < 4; ++j)
        acc[i][j] = __builtin_amdgcn_mfma_f32_16x16x32_f16(af[i], bf[j], acc[i][j], 0, 0, 0);
  }

  float b2v[4];
  #pragma unroll
  for (int j = 0; j < 4; ++j) b2v[j] = b2[wc + 16*j + ln];
  float ps[4], pq[4];
  #pragma unroll
  for (int j = 0; j < 4; ++j){ ps[j] = 0.f; pq[j] = 0.f; }
  #pragma unroll
  for (int i = 0; i < 2; ++i){
    #pragma unroll
    for (int r = 0; r < 4; ++r){
      int rg = rbase + m0 + 16*i + 4*q + r;
      if (rg < NN){
        #pragma unroll
        for (int j = 0; j < 4; ++j){
          float v = acc[i][j][r] + b2v[j];
          z2[(size_t)rg*HID + wc + 16*j + ln] = v;
          ps[j] += v; pq[j] += v*v;
        }
      }
    }
  }
  red[tid] = 0.f;
  if (tid < 128) red[128 + tid] = 0.f;
  __syncthreads();
  #pragma unroll
  for (int j = 0; j < 4; ++j){
    int c = wc + 16*j + ln;
    atomicAdd(&red[c], ps[j]);
    atomicAdd(&red[128 + c], pq[j]);
  }
  __syncthreads();
  if (tid < 128){
    atomicAdd(&bnS[tid], red[tid]);
    atomicAdd(&bnQ[tid], red[128 + tid]);
  }
}

// ======================= BN apply + ReLU -> hf (f16) =======================
__global__ void kBn(const float* __restrict__ z2, const float* __restrict__ bnS,
                    const float* __restrict__ bnQ, const float* __restrict__ gamma,
                    const float* __restrict__ beta, ushort_t* __restrict__ hf){
  int gid = blockIdx.x*256 + threadIdx.x;   // NN*64
  if (gid >= NN*64) return;
  int r = gid >> 6, c = (gid & 63)*2;
  float2 zv = *(const float2*)&z2[(size_t)r*HID + c];
  float2 sS = *(const float2*)&bnS[c];
  float2 sQ = *(const float2*)&bnQ[c];
  float2 gm = *(const float2*)&gamma[c];
  float2 bt = *(const float2*)&beta[c];
  float m0 = sS.x*(1.f/NN), m1 = sS.y*(1.f/NN);
  float v0 = sQ.x*(1.f/NN) - m0*m0, v1 = sQ.y*(1.f/NN) - m1*m1;
  float o0 = fmaxf((zv.x - m0)*rsqrtf(v0 + 1e-5f)*gm.x + bt.x, 0.f);
  float o1 = fmaxf((zv.y - m1)*rsqrtf(v1 + 1e-5f)*gm.y + bt.y, 0.f);
  *(unsigned*)&hf[(size_t)r*HID + c] = pkf16(o0, o1);
}

// ======================= pool =======================
__global__ __launch_bounds__(192) void kPool(const ushort_t* __restrict__ hf, const int* __restrict__ bid,
                      const int* __restrict__ tidx, const float* __restrict__ temb,
                      float* __restrict__ g){
  int b = blockIdx.x, t = threadIdx.x;
  int lo = 0, hi = NN;
  while (lo < hi){ int m = (lo + hi) >> 1; if (bid[m] < b) lo = m + 1; else hi = m; }
  int s = lo;
  lo = 0; hi = NN;
  while (lo < hi){ int m = (lo + hi) >> 1; if (bid[m] < b + 1) lo = m + 1; else hi = m; }
  int e = lo;
  if (t < HID){
    float acc = 0.f;
    for (int n = s; n < e; ++n) acc += h2f(hf[(size_t)n*HID + t]);
    g[b*192 + t] = acc;
  } else {
    int j = t - HID;
    g[b*192 + HID + j] = temb[tidx[b]*TE + j];
  }
}

// ======================= head MLP =======================
__global__ __launch_bounds__(128) void kHead(const float* __restrict__ g,
    const float* __restrict__ w1, const float* __restrict__ b1,
    const float* __restrict__ w2, const float* __restrict__ b2,
    const float* __restrict__ w3, const float* __restrict__ b3,
    float* __restrict__ out){
  __shared__ float gv[192];
  __shared__ float t1[128];
  __shared__ float t2[64];
  int b = blockIdx.x, t = threadIdx.x;
  gv[t] = g[b*192 + t];
  if (t < 64) gv[128 + t] = g[b*192 + 128 + t];
  __syncthreads();
  float acc = b1[t];
  for (int k = 0; k < 192; ++k) acc = fmaf(gv[k], w1[k*HID + t], acc);
  t1[t] = fmaxf(acc, 0.f);
  __syncthreads();
  if (t < 64){
    float a2 = b2[t];
    for (int k = 0; k < 128; ++k) a2 = fmaf(t1[k], w2[k*64 + t], a2);
    t2[t] = fmaxf(a2, 0.f);
  }
  __syncthreads();
  if (t == 0){
    float s = b3[0];
    for (int k = 0; k < 64; ++k) s = fmaf(t2[k], w3[k], s);
    out[b] = s;
  }
}

// ======================= launch =======================
extern "C" void kernel_launch(void* const* d_in, const int* in_sizes, int n_in,
                              void* d_out, int out_size, void* d_ws, size_t ws_size,
                              hipStream_t stream){
  const float* x     = (const float*)d_in[0];
  const int*   ei    = (const int*)  d_in[1];
  const float* eattr = (const float*)d_in[2];
  const int*   bids  = (const int*)  d_in[3];
  const int*   tgt   = (const int*)  d_in[4];
  const float* nw    = (const float*)d_in[5];
  const float* nb    = (const float*)d_in[6];
  const float* eps   = (const float*)d_in[7];
  const float* ew    = (const float*)d_in[8];
  const float* eb    = (const float*)d_in[9];
  const float* w1    = (const float*)d_in[10];
  const float* bb1   = (const float*)d_in[11];
  const float* w2    = (const float*)d_in[12];
  const float* bb2   = (const float*)d_in[13];
  const float* gam   = (const float*)d_in[14];
  const float* bet   = (const float*)d_in[15];
  const float* temb  = (const float*)d_in[16];
  const float* h1w   = (const float*)d_in[17];
  const float* h1b   = (const float*)d_in[18];
  const float* h2w   = (const float*)d_in[19];
  const float* h2b   = (const float*)d_in[20];
  const float* h3w   = (const float*)d_in[21];
  const float* h3b   = (const float*)d_in[22];
  float* out = (float*)d_out;

  ushort_t* aggb = (ushort_t*)d_ws;                     // (NN+64)*128
  ushort_t* wtb  = aggb + (size_t)(NN + 64)*HID;        // 6*16384
  ushort_t* hf   = wtb + (size_t)6*16384;               // (NN+64)*128
  unsigned* eaPos = (unsigned*)(hf + (size_t)(NN + 64)*HID); // NE*8
  float* z2  = (float*)(eaPos + (size_t)NE*8);          // NN*128
  float* g   = z2 + (size_t)NN*HID;                     // NG*192
  float* bnS = g  + (size_t)NG*192;                     // 128
  float* bnQ = bnS + HID;                               // 128
  int* offs  = (int*)(bnQ + HID);                       // NN+1
  int* cnt   = offs + NN + 1;                           // NN
  int* curs  = cnt + NN;                                // NN
  int* perm  = curs + NN;                               // NE
  int* srcPos= perm + NE;                               // NE
  int* psum  = srcPos + NE;                             // 256
  int* pofs  = psum + 256;                              // 256

  const int* esrc = ei;
  const int* edst = ei + NE;

  kConvW   <<<(6*16384 + 255)/256, 256, 0, stream>>>(w1, w2, wtb);
  kZero    <<<(NN + 255)/256, 256, 0, stream>>>(cnt, NN);
  kHist    <<<(NE + 255)/256, 256, 0, stream>>>(edst, cnt);
  kPartSum <<<SCAN_B, 256, 0, stream>>>(cnt, psum);
  kScanPart<<<1, 256, 0, stream>>>(psum, pofs, offs);
  kScanApply<<<SCAN_B, 256, 0, stream>>>(cnt, pofs, offs, curs);
  kScatter <<<(NE + 255)/256, 256, 0, stream>>>(edst, esrc, curs, perm, srcPos);
  kPermEA  <<<(NE*2 + 255)/256, 256, 0, stream>>>(eattr, perm, eaPos);
  kNodeInit<<<(NN*64 + 255)/256, 256, 0, stream>>>(x, nw, nb, hf);

  for (int l = 0; l < NL; ++l){
    kAgg<<<NB_AGG, 256, 0, stream>>>(hf, eaPos, srcPos, offs,
                                 ew + (size_t)l*EIN*HID, eb + (size_t)l*HID,
                                 aggb, bnS, bnQ);
    kMlp<<<(NN + BM - 1)/BM, 256, 0, stream>>>(aggb, hf, eps, l, z2,
                                 wtb + (size_t)l*16384, bb1 + (size_t)l*HID,
                                 wtb + (size_t)(3+l)*16384, bb2 + (size_t)l*HID,
                                 bnS, bnQ);
    kBn<<<(NN*64 + 255)/256, 256, 0, stream>>>(z2, bnS, bnQ,
                                 gam + (size_t)l*HID, bet + (size_t)l*HID, hf);
  }

  kPool<<<NG, 192, 0, stream>>>(hf, bids, tgt, temb, g);
  kHead<<<NG, 128, 0, stream>>>(g, h1w, h1b, h2w, h2b, h3w, h3b, out);
}

// Round 9
// 550.665 us; speedup vs baseline: 3.2266x; 1.1068x over previous
//
#include <hip/hip_runtime.h>

#define NN 50000
#define NE 800000
#define NIN 32
#define EIN 16
#define HID 128
#define NL 3
#define NG 256
#define TE 64
#define BM 64        // kMlp row tile
#define SCAN_B 196   // ceil(NN/256)
#define NB_AGG 4096  // kAgg blocks (x4 waves)

typedef unsigned short ushort_t;
typedef __attribute__((ext_vector_type(8))) _Float16 half8;
typedef __attribute__((ext_vector_type(4))) float f32x4;
typedef __attribute__((ext_vector_type(2))) __fp16 h2;

__device__ __forceinline__ unsigned pkf16(float a, float b){
  h2 h = __builtin_amdgcn_cvt_pkrtz(a, b);
  union{ h2 h; unsigned u; } c; c.h = h; return c.u;
}
__device__ __forceinline__ h2 u2h(unsigned u){
  union{ unsigned u; h2 h; } c; c.u = u; return c.h;
}
__device__ __forceinline__ ushort_t f2h(float x){
  union{ __fp16 h; ushort_t u; } c; c.h = (__fp16)x; return c.u;
}
__device__ __forceinline__ float h2f(ushort_t v){
  union{ ushort_t u; __fp16 h; } c; c.u = v; return (float)c.h;
}

// v_pk_fma_f16 with op_sel broadcast of src0 half (zero-cost scalar splat)
#define PKFMA_LO(a, e, w) asm("v_pk_fma_f16 %0, %1, %2, %0 op_sel:[0,0,0] op_sel_hi:[0,1,1]" : "+v"(a) : "v"(e), "v"(w))
#define PKFMA_HI(a, e, w) asm("v_pk_fma_f16 %0, %1, %2, %0 op_sel:[1,0,0] op_sel_hi:[1,1,1]" : "+v"(a) : "v"(e), "v"(w))
// acc(f32) += f16 half of t (single instruction f16->f32 accumulate)
#define FMAMIX_LO(acc, t, one) asm("v_fma_mix_f32 %0, %1, %2, %0 op_sel:[0,0,0] op_sel_hi:[1,0,0]" : "+v"(acc) : "v"(t), "v"(one))
#define FMAMIX_HI(acc, t, one) asm("v_fma_mix_f32 %0, %1, %2, %0 op_sel:[1,0,0] op_sel_hi:[1,0,0]" : "+v"(acc) : "v"(t), "v"(one))

typedef const __attribute__((address_space(1))) unsigned gas_t;
typedef __attribute__((address_space(3))) unsigned las_t;
__device__ __forceinline__ void stage16(const void* g, void* l){
  __builtin_amdgcn_global_load_lds((gas_t*)g, (las_t*)l, 16, 0, 0);
}

// ======================= CSR build (dst-sorted) =======================
__global__ void kZero(int* __restrict__ p, int n){
  int i = blockIdx.x*256 + threadIdx.x;
  if (i < n) p[i] = 0;
}

__global__ void kHist(const int* __restrict__ dst, int* __restrict__ cnt){
  int e = blockIdx.x*256 + threadIdx.x;
  if (e < NE) atomicAdd(&cnt[dst[e]], 1);
}

__global__ void kPartSum(const int* __restrict__ cnt, int* __restrict__ psum){
  __shared__ int sm[256];
  int b = blockIdx.x, t = threadIdx.x, i = b*256 + t;
  sm[t] = (i < NN) ? cnt[i] : 0;
  __syncthreads();
  for (int o = 128; o > 0; o >>= 1){
    if (t < o) sm[t] += sm[t + o];
    __syncthreads();
  }
  if (t == 0) psum[b] = sm[0];
}

__global__ __launch_bounds__(256) void kScanPart(const int* __restrict__ psum,
                                                 int* __restrict__ pofs, int* __restrict__ offs){
  __shared__ int sm[256];
  int t = threadIdx.x;
  int v = (t < SCAN_B) ? psum[t] : 0;
  sm[t] = v;
  __syncthreads();
  for (int o = 1; o < 256; o <<= 1){
    int x = (t >= o) ? sm[t - o] : 0;
    __syncthreads();
    sm[t] += x;
    __syncthreads();
  }
  if (t < SCAN_B) pofs[t] = sm[t] - v;
  if (t == 255) offs[NN] = sm[255];
}

__global__ void kScanApply(const int* __restrict__ cnt, const int* __restrict__ pofs,
                           int* __restrict__ offs, int* __restrict__ curs){
  __shared__ int sm[256];
  int b = blockIdx.x, t = threadIdx.x, i = b*256 + t;
  int v = (i < NN) ? cnt[i] : 0;
  sm[t] = v;
  __syncthreads();
  for (int o = 1; o < 256; o <<= 1){
    int x = (t >= o) ? sm[t - o] : 0;
    __syncthreads();
    sm[t] += x;
    __syncthreads();
  }
  int ex = sm[t] - v + pofs[b];
  if (i < NN){ offs[i] = ex; curs[i] = ex; }
}

// fused scatter: CSR position + src index + f16-packed edge attrs in one pass
__global__ void kScatterEA(const int* __restrict__ dst, const int* __restrict__ src,
                           const float* __restrict__ eattr,
                           int* __restrict__ curs, int* __restrict__ srcPos,
                           unsigned* __restrict__ eaPos){
  int e = blockIdx.x*256 + threadIdx.x;
  if (e >= NE) return;
  int p = atomicAdd(&curs[dst[e]], 1);
  srcPos[p] = src[e];
  const float* row = eattr + (size_t)e*EIN;
  float4 v0 = *(const float4*)row;
  float4 v1 = *(const float4*)(row + 4);
  float4 v2 = *(const float4*)(row + 8);
  float4 v3 = *(const float4*)(row + 12);
  uint4 d0, d1;
  d0.x = pkf16(v0.x, v0.y); d0.y = pkf16(v0.z, v0.w);
  d0.z = pkf16(v1.x, v1.y); d0.w = pkf16(v1.z, v1.w);
  d1.x = pkf16(v2.x, v2.y); d1.y = pkf16(v2.z, v2.w);
  d1.z = pkf16(v3.x, v3.y); d1.w = pkf16(v3.z, v3.w);
  *(uint4*)&eaPos[(size_t)p*8]     = d0;
  *(uint4*)&eaPos[(size_t)p*8 + 4] = d1;
}

// ======================= W -> f16, transposed + pre-swizzled =======================
__global__ void kConvW(const float* __restrict__ w1, const float* __restrict__ w2,
                       ushort_t* __restrict__ wtb){
  int gid = blockIdx.x*256 + threadIdx.x;
  if (gid >= 6*16384) return;
  int mat = gid >> 14, idx = gid & 16383;
  int k = idx >> 7, n = idx & 127;
  const float* src = (mat < 3) ? (w1 + (size_t)mat*16384) : (w2 + (size_t)(mat-3)*16384);
  wtb[(size_t)mat*16384 + n*128 + (k ^ ((n&7)<<3))] = f2h(src[idx]);
}

// ======================= node embed -> hf (f16) =======================
__global__ void kNodeInit(const float* __restrict__ x, const float* __restrict__ w,
                          const float* __restrict__ b, ushort_t* __restrict__ hf){
  int gid = blockIdx.x*256 + threadIdx.x;   // NN*64
  if (gid >= NN*64) return;
  int n = gid >> 6, c = (gid & 63)*2;
  const float* xr = x + (size_t)n*NIN;
  float a0 = b[c], a1 = b[c+1];
  #pragma unroll
  for (int k = 0; k < NIN; ++k){
    float xv = xr[k];
    a0 = fmaf(xv, w[k*HID + c],     a0);
    a1 = fmaf(xv, w[k*HID + c + 1], a1);
  }
  *(unsigned*)&hf[(size_t)n*HID + c] = pkf16(a0, a1);
}

// ======================= GINE aggregate: channel-pair W + op_sel pk_fma =======================
// Per edge per lane (2 channels): 16 pk_fma (op_sel broadcast) + pk_add + pk_max + 2 fma_mix.
// Writes only agg = sum_e relu(h_src + ea@W + b); self-term folded into kMlp.
__global__ __launch_bounds__(256) void kAgg(
    const ushort_t* __restrict__ hf, const unsigned* __restrict__ eaPos,
    const int* __restrict__ srcPos, const int* __restrict__ offs,
    const float* __restrict__ Wl, const float* __restrict__ bl,
    ushort_t* __restrict__ aggb, float* __restrict__ bnS, float* __restrict__ bnQ){
  __shared__ unsigned easu[4][16][8];   // [wave][edge][8 u32 = 16 f16 k-values]
  __shared__ int srcsS[4][16];
  int tid = threadIdx.x, lane = tid & 63, wv = tid >> 6;
  if (blockIdx.x == 0 && tid < 128){ bnS[tid] = 0.f; bnQ[tid] = 0.f; }
  int c0 = 2*lane;
  // channel-pair packed W columns: wP[k] = (W[k][c0], W[k][c0+1])
  h2 wP[EIN];
  #pragma unroll
  for (int k = 0; k < EIN; ++k)
    wP[k] = __builtin_amdgcn_cvt_pkrtz(Wl[k*HID + c0], Wl[k*HID + c0 + 1]);
  h2 biasP = __builtin_amdgcn_cvt_pkrtz(bl[c0], bl[c0+1]);
  float one = 1.0f;

  for (int n = blockIdx.x*4 + wv; n < NN; n += NB_AGG*4){
    int s0 = offs[n], s1 = offs[n+1];
    float acc0 = 0.f, acc1 = 0.f;

    auto BODY = [&](int i, unsigned hs){
      const uint4* A = (const uint4*)&easu[wv][i][0];
      uint4 e0 = A[0], e1 = A[1];
      h2 a = biasP;
      PKFMA_LO(a, e0.x, wP[0]);  PKFMA_HI(a, e0.x, wP[1]);
      PKFMA_LO(a, e0.y, wP[2]);  PKFMA_HI(a, e0.y, wP[3]);
      PKFMA_LO(a, e0.z, wP[4]);  PKFMA_HI(a, e0.z, wP[5]);
      PKFMA_LO(a, e0.w, wP[6]);  PKFMA_HI(a, e0.w, wP[7]);
      PKFMA_LO(a, e1.x, wP[8]);  PKFMA_HI(a, e1.x, wP[9]);
      PKFMA_LO(a, e1.y, wP[10]); PKFMA_HI(a, e1.y, wP[11]);
      PKFMA_LO(a, e1.z, wP[12]); PKFMA_HI(a, e1.z, wP[13]);
      PKFMA_LO(a, e1.w, wP[14]); PKFMA_HI(a, e1.w, wP[15]);
      h2 t = a + u2h(hs);
      h2 zz; zz[0] = (__fp16)0.f; zz[1] = (__fp16)0.f;
      t = __builtin_elementwise_max(t, zz);
      FMAMIX_LO(acc0, t, one);
      FMAMIX_HI(acc1, t, one);
    };

    for (int j = s0; j < s1; j += 16){
      int cnt = min(16, s1 - j);
      if (lane < cnt) srcsS[wv][lane] = srcPos[j + lane];
      if (lane < 4*cnt){
        int r = lane >> 2, part = lane & 3;
        *(uint2*)&easu[wv][r][part*2] = *(const uint2*)&eaPos[(size_t)(j + r)*8 + part*2];
      }
      asm volatile("s_waitcnt lgkmcnt(0)" ::: "memory");
      if (cnt == 16){
        unsigned hsv[16];
        #pragma unroll
        for (int i = 0; i < 16; ++i)
          hsv[i] = *(const unsigned*)&hf[(size_t)srcsS[wv][i]*HID + c0];
        #pragma unroll
        for (int i = 0; i < 16; ++i) BODY(i, hsv[i]);
      } else {
        for (int i = 0; i < cnt; ++i){
          unsigned hs = *(const unsigned*)&hf[(size_t)srcsS[wv][i]*HID + c0];
          BODY(i, hs);
        }
      }
      asm volatile("s_waitcnt lgkmcnt(0)" ::: "memory");  // easu reads done before overwrite
    }
    *(unsigned*)&aggb[(size_t)n*HID + c0] = pkf16(acc0, acc1);
  }
}

// ======================= fused MLP via MFMA (f16): A = (1+eps)*h + agg =======================
__global__ __launch_bounds__(256, 1) void kMlp(
    const ushort_t* __restrict__ aggb, const ushort_t* __restrict__ hf,
    const float* __restrict__ epsArr, int layer, float* __restrict__ z2,
    const ushort_t* __restrict__ w1t, const float* __restrict__ b1,
    const ushort_t* __restrict__ w2t, const float* __restrict__ b2,
    float* __restrict__ bnS, float* __restrict__ bnQ){
  __shared__ __align__(16) ushort_t As[BM*128];
  __shared__ __align__(16) ushort_t Bs[128*128];
  __shared__ float red[256];
  int tid  = threadIdx.x;
  int lane = tid & 63;
  int w    = tid >> 6;
  int ln   = tid & 15;
  int q    = (tid >> 4) & 3;
  int rbase = blockIdx.x * BM;
  int m0 = (w >> 1) * 32;
  int wc = (w & 1) * 64;

  const char* gB1 = (const char*)w1t;
  #pragma unroll
  for (int it = 0; it < 8; ++it)
    stage16(gB1 + (w*8192 + it*1024 + lane*16), (char*)Bs + (w*8192 + it*1024));
  {
    _Float16 ep1 = (_Float16)(1.f + epsArr[layer]);
    half8 ep8 = (half8)ep1;
    #pragma unroll
    for (int i = tid; i < BM*16; i += 256){
      int row = i >> 4, c8 = (i & 15) << 3;
      size_t gr = (size_t)(rbase + row)*HID + c8;
      half8 hv = *(const half8*)&hf[gr];
      half8 av = *(const half8*)&aggb[gr];
      half8 o = __builtin_elementwise_fma(hv, ep8, av);
      *(half8*)&As[row*128 + (c8 ^ ((row&7)<<3))] = o;
    }
  }
  __syncthreads();

  f32x4 acc[2][4];
  #pragma unroll
  for (int i = 0; i < 2; ++i)
    #pragma unroll
    for (int j = 0; j < 4; ++j) acc[i][j] = (f32x4)0.f;

  #pragma unroll
  for (int kk = 0; kk < 4; ++kk){
    int kb = kk*32 + q*8;
    half8 af[2], bf[4];
    #pragma unroll
    for (int i = 0; i < 2; ++i){
      int m = m0 + 16*i + ln;
      af[i] = *(const half8*)&As[m*128 + (kb ^ ((m&7)<<3))];
    }
    #pragma unroll
    for (int j = 0; j < 4; ++j){
      int nn = wc + 16*j + ln;
      bf[j] = *(const half8*)&Bs[nn*128 + (kb ^ ((nn&7)<<3))];
    }
    #pragma unroll
    for (int i = 0; i < 2; ++i)
      #pragma unroll
      for (int j = 0; j < 4; ++j)
        acc[i][j] = __builtin_amdgcn_mfma_f32_16x16x32_f16(af[i], bf[j], acc[i][j], 0, 0, 0);
  }
  __syncthreads();

  const char* gB2 = (const char*)w2t;
  #pragma unroll
  for (int it = 0; it < 8; ++it)
    stage16(gB2 + (w*8192 + it*1024 + lane*16), (char*)Bs + (w*8192 + it*1024));
  {
    float b1v[4];
    #pragma unroll
    for (int j = 0; j < 4; ++j) b1v[j] = b1[wc + 16*j + ln];
    #pragma unroll
    for (int i = 0; i < 2; ++i){
      #pragma unroll
      for (int j = 0; j < 4; ++j){
        int kc = wc + 16*j + ln;
        #pragma unroll
        for (int r = 0; r < 4; ++r){
          int m = m0 + 16*i + 4*q + r;
          As[m*128 + (kc ^ ((m&7)<<3))] = f2h(fmaxf(acc[i][j][r] + b1v[j], 0.f));
        }
      }
    }
  }
  #pragma unroll
  for (int i = 0; i < 2; ++i)
    #pragma unroll
    for (int j = 0; j < 4; ++j) acc[i][j] = (f32x4)0.f;
  __syncthreads();

  #pragma unroll
  for (int kk = 0; kk < 4; ++kk){
    int kb = kk*32 + q*8;
    half8 af[2], bf[4];
    #pragma unroll
    for (int i = 0; i < 2; ++i){
      int m = m0 + 16*i + ln;
      af[i] = *(const half8*)&As[m*128 + (kb ^ ((m&7)<<3))];
    }
    #pragma unroll
    for (int j = 0; j < 4; ++j){
      int nn = wc + 16*j + ln;
      bf[j] = *(const half8*)&Bs[nn*128 + (kb ^ ((nn&7)<<3))];
    }
    #pragma unroll
    for (int i = 0; i < 2; ++i)
      #pragma unroll
      for (int j = 0; j < 4; ++j)
        acc[i][j] = __builtin_amdgcn_mfma_f32_16x16x32_f16(af[i], bf[j], acc[i][j], 0, 0, 0);
  }

  float b2v[4];
  #pragma unroll
  for (int j = 0; j < 4; ++j) b2v[j] = b2[wc + 16*j + ln];
  float ps[4], pq[4];
  #pragma unroll
  for (int j = 0; j < 4; ++j){ ps[j] = 0.f; pq[j] = 0.f; }
  #pragma unroll
  for (int i = 0; i < 2; ++i){
    #pragma unroll
    for (int r = 0; r < 4; ++r){
      int rg = rbase + m0 + 16*i + 4*q + r;
      if (rg < NN){
        #pragma unroll
        for (int j = 0; j < 4; ++j){
          float v = acc[i][j][r] + b2v[j];
          z2[(size_t)rg*HID + wc + 16*j + ln] = v;
          ps[j] += v; pq[j] += v*v;
        }
      }
    }
  }
  red[tid] = 0.f;
  if (tid < 128) red[128 + tid] = 0.f;
  __syncthreads();
  #pragma unroll
  for (int j = 0; j < 4; ++j){
    int c = wc + 16*j + ln;
    atomicAdd(&red[c], ps[j]);
    atomicAdd(&red[128 + c], pq[j]);
  }
  __syncthreads();
  if (tid < 128){
    atomicAdd(&bnS[tid], red[tid]);
    atomicAdd(&bnQ[tid], red[128 + tid]);
  }
}

// ======================= BN apply + ReLU -> hf (f16) =======================
__global__ void kBn(const float* __restrict__ z2, const float* __restrict__ bnS,
                    const float* __restrict__ bnQ, const float* __restrict__ gamma,
                    const float* __restrict__ beta, ushort_t* __restrict__ hf){
  int gid = blockIdx.x*256 + threadIdx.x;   // NN*64
  if (gid >= NN*64) return;
  int r = gid >> 6, c = (gid & 63)*2;
  float2 zv = *(const float2*)&z2[(size_t)r*HID + c];
  float2 sS = *(const float2*)&bnS[c];
  float2 sQ = *(const float2*)&bnQ[c];
  float2 gm = *(const float2*)&gamma[c];
  float2 bt = *(const float2*)&beta[c];
  float m0 = sS.x*(1.f/NN), m1 = sS.y*(1.f/NN);
  float v0 = sQ.x*(1.f/NN) - m0*m0, v1 = sQ.y*(1.f/NN) - m1*m1;
  float o0 = fmaxf((zv.x - m0)*rsqrtf(v0 + 1e-5f)*gm.x + bt.x, 0.f);
  float o1 = fmaxf((zv.y - m1)*rsqrtf(v1 + 1e-5f)*gm.y + bt.y, 0.f);
  *(unsigned*)&hf[(size_t)r*HID + c] = pkf16(o0, o1);
}

// ======================= fused pool + head =======================
__global__ __launch_bounds__(192) void kPoolHead(const ushort_t* __restrict__ hf,
    const int* __restrict__ bid, const int* __restrict__ tidx,
    const float* __restrict__ temb,
    const float* __restrict__ w1, const float* __restrict__ b1,
    const float* __restrict__ w2, const float* __restrict__ b2,
    const float* __restrict__ w3, const float* __restrict__ b3,
    float* __restrict__ out){
  __shared__ float gv[192];
  __shared__ float t1[128];
  __shared__ float t2[64];
  int b = blockIdx.x, t = threadIdx.x;
  int lo = 0, hi = NN;
  while (lo < hi){ int m = (lo + hi) >> 1; if (bid[m] < b) lo = m + 1; else hi = m; }
  int s = lo;
  lo = 0; hi = NN;
  while (lo < hi){ int m = (lo + hi) >> 1; if (bid[m] < b + 1) lo = m + 1; else hi = m; }
  int e = lo;
  if (t < HID){
    float acc = 0.f;
    for (int n = s; n < e; ++n) acc += h2f(hf[(size_t)n*HID + t]);
    gv[t] = acc;
  } else {
    gv[t] = temb[tidx[b]*TE + (t - HID)];
  }
  __syncthreads();
  float acc = b1[t & 127];
  if (t < HID){
    for (int k = 0; k < 192; ++k) acc = fmaf(gv[k], w1[k*HID + t], acc);
    t1[t] = fmaxf(acc, 0.f);
  }
  __syncthreads();
  if (t < 64){
    float a2 = b2[t];
    for (int k = 0; k < 128; ++k) a2 = fmaf(t1[k], w2[k*64 + t], a2);
    t2[t] = fmaxf(a2, 0.f);
  }
  __syncthreads();
  if (t == 0){
    float sv = b3[0];
    for (int k = 0; k < 64; ++k) sv = fmaf(t2[k], w3[k], sv);
    out[b] = sv;
  }
}

// ======================= launch =======================
extern "C" void kernel_launch(void* const* d_in, const int* in_sizes, int n_in,
                              void* d_out, int out_size, void* d_ws, size_t ws_size,
                              hipStream_t stream){
  const float* x     = (const float*)d_in[0];
  const int*   ei    = (const int*)  d_in[1];
  const float* eattr = (const float*)d_in[2];
  const int*   bids  = (const int*)  d_in[3];
  const int*   tgt   = (const int*)  d_in[4];
  const float* nw    = (const float*)d_in[5];
  const float* nb    = (const float*)d_in[6];
  const float* eps   = (const float*)d_in[7];
  const float* ew    = (const float*)d_in[8];
  const float* eb    = (const float*)d_in[9];
  const float* w1    = (const float*)d_in[10];
  const float* bb1   = (const float*)d_in[11];
  const float* w2    = (const float*)d_in[12];
  const float* bb2   = (const float*)d_in[13];
  const float* gam   = (const float*)d_in[14];
  const float* bet   = (const float*)d_in[15];
  const float* temb  = (const float*)d_in[16];
  const float* h1w   = (const float*)d_in[17];
  const float* h1b   = (const float*)d_in[18];
  const float* h2w   = (const float*)d_in[19];
  const float* h2b   = (const float*)d_in[20];
  const float* h3w   = (const float*)d_in[21];
  const float* h3b   = (const float*)d_in[22];
  float* out = (float*)d_out;

  ushort_t* aggb = (ushort_t*)d_ws;                     // (NN+64)*128
  ushort_t* wtb  = aggb + (size_t)(NN + 64)*HID;        // 6*16384
  ushort_t* hf   = wtb + (size_t)6*16384;               // (NN+64)*128
  unsigned* eaPos = (unsigned*)(hf + (size_t)(NN + 64)*HID); // NE*8
  float* z2  = (float*)(eaPos + (size_t)NE*8);          // NN*128
  float* bnS = z2 + (size_t)NN*HID;                     // 128
  float* bnQ = bnS + HID;                               // 128
  int* offs  = (int*)(bnQ + HID);                       // NN+1
  int* cnt   = offs + NN + 1;                           // NN
  int* curs  = cnt + NN;                                // NN
  int* srcPos= curs + NN;                               // NE
  int* psum  = srcPos + NE;                             // 256
  int* pofs  = psum + 256;                              // 256

  const int* esrc = ei;
  const int* edst = ei + NE;

  kConvW   <<<(6*16384 + 255)/256, 256, 0, stream>>>(w1, w2, wtb);
  kZero    <<<(NN + 255)/256, 256, 0, stream>>>(cnt, NN);
  kHist    <<<(NE + 255)/256, 256, 0, stream>>>(edst, cnt);
  kPartSum <<<SCAN_B, 256, 0, stream>>>(cnt, psum);
  kScanPart<<<1, 256, 0, stream>>>(psum, pofs, offs);
  kScanApply<<<SCAN_B, 256, 0, stream>>>(cnt, pofs, offs, curs);
  kScatterEA<<<(NE + 255)/256, 256, 0, stream>>>(edst, esrc, eattr, curs, srcPos, eaPos);
  kNodeInit<<<(NN*64 + 255)/256, 256, 0, stream>>>(x, nw, nb, hf);

  for (int l = 0; l < NL; ++l){
    kAgg<<<NB_AGG, 256, 0, stream>>>(hf, eaPos, srcPos, offs,
                                 ew + (size_t)l*EIN*HID, eb + (size_t)l*HID,
                                 aggb, bnS, bnQ);
    kMlp<<<(NN + BM - 1)/BM, 256, 0, stream>>>(aggb, hf, eps, l, z2,
                                 wtb + (size_t)l*16384, bb1 + (size_t)l*HID,
                                 wtb + (size_t)(3+l)*16384, bb2 + (size_t)l*HID,
                                 bnS, bnQ);
    kBn<<<(NN*64 + 255)/256, 256, 0, stream>>>(z2, bnS, bnQ,
                                 gam + (size_t)l*HID, bet + (size_t)l*HID, hf);
  }

  kPoolHead<<<NG, 192, 0, stream>>>(hf, bids, tgt, temb,
                                    h1w, h1b, h2w, h2b, h3w, h3b, out);
}

// Round 10
// 528.096 us; speedup vs baseline: 3.3645x; 1.0427x over previous
//
#include <hip/hip_runtime.h>

#define NN 50000
#define NE 800000
#define NIN 32
#define EIN 16
#define HID 128
#define NL 3
#define NG 256
#define TE 64
#define BM 64        // kMlp row tile
#define SCAN_B 196   // ceil(NN/256)
#define NB_AGG 4096  // kAgg blocks (x4 waves)

typedef unsigned short ushort_t;
typedef __attribute__((ext_vector_type(8))) _Float16 half8;
typedef __attribute__((ext_vector_type(4))) float f32x4;
typedef __attribute__((ext_vector_type(2))) __fp16 h2;

__device__ __forceinline__ unsigned pkf16(float a, float b){
  h2 h = __builtin_amdgcn_cvt_pkrtz(a, b);
  union{ h2 h; unsigned u; } c; c.h = h; return c.u;
}
__device__ __forceinline__ h2 u2h(unsigned u){
  union{ unsigned u; h2 h; } c; c.u = u; return c.h;
}
__device__ __forceinline__ unsigned h2u(h2 h){
  union{ h2 h; unsigned u; } c; c.h = h; return c.u;
}
__device__ __forceinline__ ushort_t f2h(float x){
  union{ __fp16 h; ushort_t u; } c; c.h = (__fp16)x; return c.u;
}
__device__ __forceinline__ float h2f(ushort_t v){
  union{ ushort_t u; __fp16 h; } c; c.u = v; return (float)c.h;
}

// v_pk_fma_f16 with op_sel broadcast of src0 half (zero-cost scalar splat)
#define PKFMA_LO(a, e, w) asm("v_pk_fma_f16 %0, %1, %2, %0 op_sel:[0,0,0] op_sel_hi:[0,1,1]" : "+v"(a) : "v"(e), "v"(w))
#define PKFMA_HI(a, e, w) asm("v_pk_fma_f16 %0, %1, %2, %0 op_sel:[1,0,0] op_sel_hi:[1,1,1]" : "+v"(a) : "v"(e), "v"(w))
// acc(f32) += f16 half of t (single instruction f16->f32 accumulate)
#define FMAMIX_LO(acc, t, one) asm("v_fma_mix_f32 %0, %1, %2, %0 op_sel:[0,0,0] op_sel_hi:[1,0,0]" : "+v"(acc) : "v"(t), "v"(one))
#define FMAMIX_HI(acc, t, one) asm("v_fma_mix_f32 %0, %1, %2, %0 op_sel:[1,0,0] op_sel_hi:[1,0,0]" : "+v"(acc) : "v"(t), "v"(one))

typedef const __attribute__((address_space(1))) unsigned gas_t;
typedef __attribute__((address_space(3))) unsigned las_t;
__device__ __forceinline__ void stage16(const void* g, void* l){
  __builtin_amdgcn_global_load_lds((gas_t*)g, (las_t*)l, 16, 0, 0);
}

// ======================= CSR build (dst-sorted) =======================
__global__ void kZero(int* __restrict__ p, int n){
  int i = blockIdx.x*256 + threadIdx.x;
  if (i < n) p[i] = 0;
}

__global__ void kHist(const int* __restrict__ dst, int* __restrict__ cnt){
  int e = blockIdx.x*256 + threadIdx.x;
  if (e < NE) atomicAdd(&cnt[dst[e]], 1);
}

__global__ void kPartSum(const int* __restrict__ cnt, int* __restrict__ psum){
  __shared__ int sm[256];
  int b = blockIdx.x, t = threadIdx.x, i = b*256 + t;
  sm[t] = (i < NN) ? cnt[i] : 0;
  __syncthreads();
  for (int o = 128; o > 0; o >>= 1){
    if (t < o) sm[t] += sm[t + o];
    __syncthreads();
  }
  if (t == 0) psum[b] = sm[0];
}

__global__ __launch_bounds__(256) void kScanPart(const int* __restrict__ psum,
                                                 int* __restrict__ pofs, int* __restrict__ offs){
  __shared__ int sm[256];
  int t = threadIdx.x;
  int v = (t < SCAN_B) ? psum[t] : 0;
  sm[t] = v;
  __syncthreads();
  for (int o = 1; o < 256; o <<= 1){
    int x = (t >= o) ? sm[t - o] : 0;
    __syncthreads();
    sm[t] += x;
    __syncthreads();
  }
  if (t < SCAN_B) pofs[t] = sm[t] - v;
  if (t == 255) offs[NN] = sm[255];
}

__global__ void kScanApply(const int* __restrict__ cnt, const int* __restrict__ pofs,
                           int* __restrict__ offs, int* __restrict__ curs){
  __shared__ int sm[256];
  int b = blockIdx.x, t = threadIdx.x, i = b*256 + t;
  int v = (i < NN) ? cnt[i] : 0;
  sm[t] = v;
  __syncthreads();
  for (int o = 1; o < 256; o <<= 1){
    int x = (t >= o) ? sm[t - o] : 0;
    __syncthreads();
    sm[t] += x;
    __syncthreads();
  }
  int ex = sm[t] - v + pofs[b];
  if (i < NN){ offs[i] = ex; curs[i] = ex; }
}

// scatter only the permutation (4B) — minimal scattered-write footprint
__global__ void kScatterPerm(const int* __restrict__ dst, int* __restrict__ curs,
                             int* __restrict__ perm){
  int e = blockIdx.x*256 + threadIdx.x;
  if (e < NE){
    int p = atomicAdd(&curs[dst[e]], 1);
    perm[p] = e;
  }
}

// gather side: coalesced over CSR positions; eattr rows are 64B-aligned full sectors
__global__ void kGatherEA(const int* __restrict__ perm, const int* __restrict__ src,
                          const float* __restrict__ eattr,
                          int* __restrict__ srcPos, unsigned* __restrict__ eaPos){
  int p = blockIdx.x*256 + threadIdx.x;
  if (p >= NE) return;
  int e = perm[p];
  srcPos[p] = src[e];
  const float4* row = (const float4*)(eattr + (size_t)e*EIN);
  float4 v0 = row[0], v1 = row[1], v2 = row[2], v3 = row[3];
  uint4 d0, d1;
  d0.x = pkf16(v0.x, v0.y); d0.y = pkf16(v0.z, v0.w);
  d0.z = pkf16(v1.x, v1.y); d0.w = pkf16(v1.z, v1.w);
  d1.x = pkf16(v2.x, v2.y); d1.y = pkf16(v2.z, v2.w);
  d1.z = pkf16(v3.x, v3.y); d1.w = pkf16(v3.z, v3.w);
  *(uint4*)&eaPos[(size_t)p*8]     = d0;
  *(uint4*)&eaPos[(size_t)p*8 + 4] = d1;
}

// ======================= W -> f16: MLP (transposed+swizzled) + node-embed (linear) =======================
__global__ void kConvW(const float* __restrict__ w1, const float* __restrict__ w2,
                       const float* __restrict__ nw,
                       ushort_t* __restrict__ wtb, ushort_t* __restrict__ wemb2){
  int gid = blockIdx.x*256 + threadIdx.x;
  if (gid < 6*16384){
    int mat = gid >> 14, idx = gid & 16383;
    int k = idx >> 7, n = idx & 127;
    const float* src = (mat < 3) ? (w1 + (size_t)mat*16384) : (w2 + (size_t)(mat-3)*16384);
    wtb[(size_t)mat*16384 + n*128 + (k ^ ((n&7)<<3))] = f2h(src[idx]);
  } else if (gid < 6*16384 + NIN*HID){
    int i = gid - 6*16384;          // i = k*128 + c
    wemb2[i] = f2h(nw[i]);
  }
}

// ======================= node embed -> hf (f16), LDS-staged =======================
// block = 16 nodes; x staged (padded rows), w f16 staged via global_load_lds.
__global__ __launch_bounds__(256) void kNodeInit2(const float* __restrict__ x,
    const ushort_t* __restrict__ wemb2, const float* __restrict__ b,
    ushort_t* __restrict__ hf){
  __shared__ float xS[16*33];                     // +1 pad: kill 4-way bank conflict
  __shared__ __align__(16) ushort_t wS[NIN*HID];  // 8KB
  int t = threadIdx.x;
  int nb = blockIdx.x*16;
  {
    float2 v = *(const float2*)(x + (size_t)nb*NIN + t*2);
    int idx = t*2;                                // 0..510
    int r = idx >> 5, k = idx & 31;
    xS[r*33 + k]     = v.x;
    xS[r*33 + k + 1] = v.y;                       // k even -> k+1 <= 31 ok
  }
  stage16((const char*)wemb2 + t*16,        (char*)wS + t*16);
  stage16((const char*)wemb2 + 4096 + t*16, (char*)wS + 4096 + t*16);
  __syncthreads();

  int r = t >> 4, c0 = (t & 15)*8;
  h2 a0, a1, a2, a3;
  a0 = a1 = a2 = a3 = u2h(0u);
  #pragma unroll
  for (int k = 0; k < NIN; ++k){
    float xk = xS[r*33 + k];
    h2 xp = __builtin_amdgcn_cvt_pkrtz(xk, xk);
    uint4 wv = *(const uint4*)&wS[k*HID + c0];
    a0 = __builtin_elementwise_fma(xp, u2h(wv.x), a0);
    a1 = __builtin_elementwise_fma(xp, u2h(wv.y), a1);
    a2 = __builtin_elementwise_fma(xp, u2h(wv.z), a2);
    a3 = __builtin_elementwise_fma(xp, u2h(wv.w), a3);
  }
  float4 bv0 = *(const float4*)&b[c0];
  float4 bv1 = *(const float4*)&b[c0 + 4];
  a0 = a0 + __builtin_amdgcn_cvt_pkrtz(bv0.x, bv0.y);
  a1 = a1 + __builtin_amdgcn_cvt_pkrtz(bv0.z, bv0.w);
  a2 = a2 + __builtin_amdgcn_cvt_pkrtz(bv1.x, bv1.y);
  a3 = a3 + __builtin_amdgcn_cvt_pkrtz(bv1.z, bv1.w);
  uint4 o;
  o.x = h2u(a0); o.y = h2u(a1); o.z = h2u(a2); o.w = h2u(a3);
  *(uint4*)&hf[(size_t)(nb + r)*HID + c0] = o;
}

// ======================= GINE aggregate: channel-pair W + op_sel pk_fma =======================
__global__ __launch_bounds__(256) void kAgg(
    const ushort_t* __restrict__ hf, const unsigned* __restrict__ eaPos,
    const int* __restrict__ srcPos, const int* __restrict__ offs,
    const float* __restrict__ Wl, const float* __restrict__ bl,
    ushort_t* __restrict__ aggb, float* __restrict__ bnS, float* __restrict__ bnQ){
  __shared__ unsigned easu[4][16][8];   // [wave][edge][8 u32 = 16 f16 k-values]
  __shared__ int srcsS[4][16];
  int tid = threadIdx.x, lane = tid & 63, wv = tid >> 6;
  if (blockIdx.x == 0 && tid < 128){ bnS[tid] = 0.f; bnQ[tid] = 0.f; }
  int c0 = 2*lane;
  h2 wP[EIN];
  #pragma unroll
  for (int k = 0; k < EIN; ++k)
    wP[k] = __builtin_amdgcn_cvt_pkrtz(Wl[k*HID + c0], Wl[k*HID + c0 + 1]);
  h2 biasP = __builtin_amdgcn_cvt_pkrtz(bl[c0], bl[c0+1]);
  float one = 1.0f;

  for (int n = blockIdx.x*4 + wv; n < NN; n += NB_AGG*4){
    int s0 = offs[n], s1 = offs[n+1];
    float acc0 = 0.f, acc1 = 0.f;

    auto BODY = [&](int i, unsigned hs){
      const uint4* A = (const uint4*)&easu[wv][i][0];
      uint4 e0 = A[0], e1 = A[1];
      h2 a = biasP;
      PKFMA_LO(a, e0.x, wP[0]);  PKFMA_HI(a, e0.x, wP[1]);
      PKFMA_LO(a, e0.y, wP[2]);  PKFMA_HI(a, e0.y, wP[3]);
      PKFMA_LO(a, e0.z, wP[4]);  PKFMA_HI(a, e0.z, wP[5]);
      PKFMA_LO(a, e0.w, wP[6]);  PKFMA_HI(a, e0.w, wP[7]);
      PKFMA_LO(a, e1.x, wP[8]);  PKFMA_HI(a, e1.x, wP[9]);
      PKFMA_LO(a, e1.y, wP[10]); PKFMA_HI(a, e1.y, wP[11]);
      PKFMA_LO(a, e1.z, wP[12]); PKFMA_HI(a, e1.z, wP[13]);
      PKFMA_LO(a, e1.w, wP[14]); PKFMA_HI(a, e1.w, wP[15]);
      h2 t = a + u2h(hs);
      h2 zz; zz[0] = (__fp16)0.f; zz[1] = (__fp16)0.f;
      t = __builtin_elementwise_max(t, zz);
      FMAMIX_LO(acc0, t, one);
      FMAMIX_HI(acc1, t, one);
    };

    for (int j = s0; j < s1; j += 16){
      int cnt = min(16, s1 - j);
      if (lane < cnt) srcsS[wv][lane] = srcPos[j + lane];
      if (lane < 4*cnt){
        int r = lane >> 2, part = lane & 3;
        *(uint2*)&easu[wv][r][part*2] = *(const uint2*)&eaPos[(size_t)(j + r)*8 + part*2];
      }
      asm volatile("s_waitcnt lgkmcnt(0)" ::: "memory");
      if (cnt == 16){
        unsigned hsv[16];
        #pragma unroll
        for (int i = 0; i < 16; ++i)
          hsv[i] = *(const unsigned*)&hf[(size_t)srcsS[wv][i]*HID + c0];
        #pragma unroll
        for (int i = 0; i < 16; ++i) BODY(i, hsv[i]);
      } else {
        for (int i = 0; i < cnt; ++i){
          unsigned hs = *(const unsigned*)&hf[(size_t)srcsS[wv][i]*HID + c0];
          BODY(i, hs);
        }
      }
      asm volatile("s_waitcnt lgkmcnt(0)" ::: "memory");
    }
    *(unsigned*)&aggb[(size_t)n*HID + c0] = pkf16(acc0, acc1);
  }
}

// ======================= fused MLP via MFMA (f16): A = (1+eps)*h + agg =======================
__global__ __launch_bounds__(256, 1) void kMlp(
    const ushort_t* __restrict__ aggb, const ushort_t* __restrict__ hf,
    const float* __restrict__ epsArr, int layer, float* __restrict__ z2,
    const ushort_t* __restrict__ w1t, const float* __restrict__ b1,
    const ushort_t* __restrict__ w2t, const float* __restrict__ b2,
    float* __restrict__ bnS, float* __restrict__ bnQ){
  __shared__ __align__(16) ushort_t As[BM*128];
  __shared__ __align__(16) ushort_t Bs[128*128];
  __shared__ float red[256];
  int tid  = threadIdx.x;
  int lane = tid & 63;
  int w    = tid >> 6;
  int ln   = tid & 15;
  int q    = (tid >> 4) & 3;
  int rbase = blockIdx.x * BM;
  int m0 = (w >> 1) * 32;
  int wc = (w & 1) * 64;

  const char* gB1 = (const char*)w1t;
  #pragma unroll
  for (int it = 0; it < 8; ++it)
    stage16(gB1 + (w*8192 + it*1024 + lane*16), (char*)Bs + (w*8192 + it*1024));
  {
    _Float16 ep1 = (_Float16)(1.f + epsArr[layer]);
    half8 ep8 = (half8)ep1;
    #pragma unroll
    for (int i = tid; i < BM*16; i += 256){
      int row = i >> 4, c8 = (i & 15) << 3;
      size_t gr = (size_t)(rbase + row)*HID + c8;
      half8 hv = *(const half8*)&hf[gr];
      half8 av = *(const half8*)&aggb[gr];
      half8 o = __builtin_elementwise_fma(hv, ep8, av);
      *(half8*)&As[row*128 + (c8 ^ ((row&7)<<3))] = o;
    }
  }
  __syncthreads();

  f32x4 acc[2][4];
  #pragma unroll
  for (int i = 0; i < 2; ++i)
    #pragma unroll
    for (int j = 0; j < 4; ++j) acc[i][j] = (f32x4)0.f;

  #pragma unroll
  for (int kk = 0; kk < 4; ++kk){
    int kb = kk*32 + q*8;
    half8 af[2], bf[4];
    #pragma unroll
    for (int i = 0; i < 2; ++i){
      int m = m0 + 16*i + ln;
      af[i] = *(const half8*)&As[m*128 + (kb ^ ((m&7)<<3))];
    }
    #pragma unroll
    for (int j = 0; j < 4; ++j){
      int nn = wc + 16*j + ln;
      bf[j] = *(const half8*)&Bs[nn*128 + (kb ^ ((nn&7)<<3))];
    }
    #pragma unroll
    for (int i = 0; i < 2; ++i)
      #pragma unroll
      for (int j = 0; j < 4; ++j)
        acc[i][j] = __builtin_amdgcn_mfma_f32_16x16x32_f16(af[i], bf[j], acc[i][j], 0, 0, 0);
  }
  __syncthreads();

  const char* gB2 = (const char*)w2t;
  #pragma unroll
  for (int it = 0; it < 8; ++it)
    stage16(gB2 + (w*8192 + it*1024 + lane*16), (char*)Bs + (w*8192 + it*1024));
  {
    float b1v[4];
    #pragma unroll
    for (int j = 0; j < 4; ++j) b1v[j] = b1[wc + 16*j + ln];
    #pragma unroll
    for (int i = 0; i < 2; ++i){
      #pragma unroll
      for (int j = 0; j < 4; ++j){
        int kc = wc + 16*j + ln;
        #pragma unroll
        for (int r = 0; r < 4; ++r){
          int m = m0 + 16*i + 4*q + r;
          As[m*128 + (kc ^ ((m&7)<<3))] = f2h(fmaxf(acc[i][j][r] + b1v[j], 0.f));
        }
      }
    }
  }
  #pragma unroll
  for (int i = 0; i < 2; ++i)
    #pragma unroll
    for (int j = 0; j < 4; ++j) acc[i][j] = (f32x4)0.f;
  __syncthreads();

  #pragma unroll
  for (int kk = 0; kk < 4; ++kk){
    int kb = kk*32 + q*8;
    half8 af[2], bf[4];
    #pragma unroll
    for (int i = 0; i < 2; ++i){
      int m = m0 + 16*i + ln;
      af[i] = *(const half8*)&As[m*128 + (kb ^ ((m&7)<<3))];
    }
    #pragma unroll
    for (int j = 0; j < 4; ++j){
      int nn = wc + 16*j + ln;
      bf[j] = *(const half8*)&Bs[nn*128 + (kb ^ ((nn&7)<<3))];
    }
    #pragma unroll
    for (int i = 0; i < 2; ++i)
      #pragma unroll
      for (int j = 0; j < 4; ++j)
        acc[i][j] = __builtin_amdgcn_mfma_f32_16x16x32_f16(af[i], bf[j], acc[i][j], 0, 0, 0);
  }

  float b2v[4];
  #pragma unroll
  for (int j = 0; j < 4; ++j) b2v[j] = b2[wc + 16*j + ln];
  float ps[4], pq[4];
  #pragma unroll
  for (int j = 0; j < 4; ++j){ ps[j] = 0.f; pq[j] = 0.f; }
  #pragma unroll
  for (int i = 0; i < 2; ++i){
    #pragma unroll
    for (int r = 0; r < 4; ++r){
      int rg = rbase + m0 + 16*i + 4*q + r;
      if (rg < NN){
        #pragma unroll
        for (int j = 0; j < 4; ++j){
          float v = acc[i][j][r] + b2v[j];
          z2[(size_t)rg*HID + wc + 16*j + ln] = v;
          ps[j] += v; pq[j] += v*v;
        }
      }
    }
  }
  red[tid] = 0.f;
  if (tid < 128) red[128 + tid] = 0.f;
  __syncthreads();
  #pragma unroll
  for (int j = 0; j < 4; ++j){
    int c = wc + 16*j + ln;
    atomicAdd(&red[c], ps[j]);
    atomicAdd(&red[128 + c], pq[j]);
  }
  __syncthreads();
  if (tid < 128){
    atomicAdd(&bnS[tid], red[tid]);
    atomicAdd(&bnQ[tid], red[128 + tid]);
  }
}

// ======================= BN apply + ReLU -> hf (f16) =======================
__global__ void kBn(const float* __restrict__ z2, const float* __restrict__ bnS,
                    const float* __restrict__ bnQ, const float* __restrict__ gamma,
                    const float* __restrict__ beta, ushort_t* __restrict__ hf){
  int gid = blockIdx.x*256 + threadIdx.x;   // NN*64
  if (gid >= NN*64) return;
  int r = gid >> 6, c = (gid & 63)*2;
  float2 zv = *(const float2*)&z2[(size_t)r*HID + c];
  float2 sS = *(const float2*)&bnS[c];
  float2 sQ = *(const float2*)&bnQ[c];
  float2 gm = *(const float2*)&gamma[c];
  float2 bt = *(const float2*)&beta[c];
  float m0 = sS.x*(1.f/NN), m1 = sS.y*(1.f/NN);
  float v0 = sQ.x*(1.f/NN) - m0*m0, v1 = sQ.y*(1.f/NN) - m1*m1;
  float o0 = fmaxf((zv.x - m0)*rsqrtf(v0 + 1e-5f)*gm.x + bt.x, 0.f);
  float o1 = fmaxf((zv.y - m1)*rsqrtf(v1 + 1e-5f)*gm.y + bt.y, 0.f);
  *(unsigned*)&hf[(size_t)r*HID + c] = pkf16(o0, o1);
}

// ======================= fused pool + head =======================
__global__ __launch_bounds__(192) void kPoolHead(const ushort_t* __restrict__ hf,
    const int* __restrict__ bid, const int* __restrict__ tidx,
    const float* __restrict__ temb,
    const float* __restrict__ w1, const float* __restrict__ b1,
    const float* __restrict__ w2, const float* __restrict__ b2,
    const float* __restrict__ w3, const float* __restrict__ b3,
    float* __restrict__ out){
  __shared__ float gv[192];
  __shared__ float t1[128];
  __shared__ float t2[64];
  int b = blockIdx.x, t = threadIdx.x;
  int lo = 0, hi = NN;
  while (lo < hi){ int m = (lo + hi) >> 1; if (bid[m] < b) lo = m + 1; else hi = m; }
  int s = lo;
  lo = 0; hi = NN;
  while (lo < hi){ int m = (lo + hi) >> 1; if (bid[m] < b + 1) lo = m + 1; else hi = m; }
  int e = lo;
  if (t < HID){
    float acc = 0.f;
    for (int n = s; n < e; ++n) acc += h2f(hf[(size_t)n*HID + t]);
    gv[t] = acc;
  } else {
    gv[t] = temb[tidx[b]*TE + (t - HID)];
  }
  __syncthreads();
  float acc = b1[t & 127];
  if (t < HID){
    for (int k = 0; k < 192; ++k) acc = fmaf(gv[k], w1[k*HID + t], acc);
    t1[t] = fmaxf(acc, 0.f);
  }
  __syncthreads();
  if (t < 64){
    float a2 = b2[t];
    for (int k = 0; k < 128; ++k) a2 = fmaf(t1[k], w2[k*64 + t], a2);
    t2[t] = fmaxf(a2, 0.f);
  }
  __syncthreads();
  if (t == 0){
    float sv = b3[0];
    for (int k = 0; k < 64; ++k) sv = fmaf(t2[k], w3[k], sv);
    out[b] = sv;
  }
}

// ======================= launch =======================
extern "C" void kernel_launch(void* const* d_in, const int* in_sizes, int n_in,
                              void* d_out, int out_size, void* d_ws, size_t ws_size,
                              hipStream_t stream){
  const float* x     = (const float*)d_in[0];
  const int*   ei    = (const int*)  d_in[1];
  const float* eattr = (const float*)d_in[2];
  const int*   bids  = (const int*)  d_in[3];
  const int*   tgt   = (const int*)  d_in[4];
  const float* nw    = (const float*)d_in[5];
  const float* nb    = (const float*)d_in[6];
  const float* eps   = (const float*)d_in[7];
  const float* ew    = (const float*)d_in[8];
  const float* eb    = (const float*)d_in[9];
  const float* w1    = (const float*)d_in[10];
  const float* bb1   = (const float*)d_in[11];
  const float* w2    = (const float*)d_in[12];
  const float* bb2   = (const float*)d_in[13];
  const float* gam   = (const float*)d_in[14];
  const float* bet   = (const float*)d_in[15];
  const float* temb  = (const float*)d_in[16];
  const float* h1w   = (const float*)d_in[17];
  const float* h1b   = (const float*)d_in[18];
  const float* h2w   = (const float*)d_in[19];
  const float* h2b   = (const float*)d_in[20];
  const float* h3w   = (const float*)d_in[21];
  const float* h3b   = (const float*)d_in[22];
  float* out = (float*)d_out;

  ushort_t* aggb = (ushort_t*)d_ws;                     // (NN+64)*128
  ushort_t* wtb  = aggb + (size_t)(NN + 64)*HID;        // 6*16384
  ushort_t* wemb2= wtb + (size_t)6*16384;               // NIN*HID
  ushort_t* hf   = wemb2 + (size_t)NIN*HID;             // (NN+64)*128
  unsigned* eaPos = (unsigned*)(hf + (size_t)(NN + 64)*HID); // NE*8
  float* z2  = (float*)(eaPos + (size_t)NE*8);          // NN*128
  float* bnS = z2 + (size_t)NN*HID;                     // 128
  float* bnQ = bnS + HID;                               // 128
  int* offs  = (int*)(bnQ + HID);                       // NN+1
  int* cnt   = offs + NN + 1;                           // NN
  int* curs  = cnt + NN;                                // NN
  int* perm  = curs + NN;                               // NE
  int* srcPos= perm + NE;                               // NE
  int* psum  = srcPos + NE;                             // 256
  int* pofs  = psum + 256;                              // 256

  const int* esrc = ei;
  const int* edst = ei + NE;

  kConvW      <<<(6*16384 + NIN*HID + 255)/256, 256, 0, stream>>>(w1, w2, nw, wtb, wemb2);
  kZero       <<<(NN + 255)/256, 256, 0, stream>>>(cnt, NN);
  kHist       <<<(NE + 255)/256, 256, 0, stream>>>(edst, cnt);
  kPartSum    <<<SCAN_B, 256, 0, stream>>>(cnt, psum);
  kScanPart   <<<1, 256, 0, stream>>>(psum, pofs, offs);
  kScanApply  <<<SCAN_B, 256, 0, stream>>>(cnt, pofs, offs, curs);
  kScatterPerm<<<(NE + 255)/256, 256, 0, stream>>>(edst, curs, perm);
  kGatherEA   <<<(NE + 255)/256, 256, 0, stream>>>(perm, esrc, eattr, srcPos, eaPos);
  kNodeInit2  <<<NN/16, 256, 0, stream>>>(x, wemb2, nb, hf);

  for (int l = 0; l < NL; ++l){
    kAgg<<<NB_AGG, 256, 0, stream>>>(hf, eaPos, srcPos, offs,
                                 ew + (size_t)l*EIN*HID, eb + (size_t)l*HID,
                                 aggb, bnS, bnQ);
    kMlp<<<(NN + BM - 1)/BM, 256, 0, stream>>>(aggb, hf, eps, l, z2,
                                 wtb + (size_t)l*16384, bb1 + (size_t)l*HID,
                                 wtb + (size_t)(3+l)*16384, bb2 + (size_t)l*HID,
                                 bnS, bnQ);
    kBn<<<(NN*64 + 255)/256, 256, 0, stream>>>(z2, bnS, bnQ,
                                 gam + (size_t)l*HID, bet + (size_t)l*HID, hf);
  }

  kPoolHead<<<NG, 192, 0, stream>>>(hf, bids, tgt, temb,
                                    h1w, h1b, h2w, h2b, h3w, h3b, out);
}